// Round 5
// baseline (1002.417 us; speedup 1.0000x reference)
//
#include <hip/hip_runtime.h>
#include <math.h>

#define F_IN 512
#define NCLS 40
#define BSH 7                 // 128 nodes per bucket
#define BNODES (1 << BSH)

typedef __attribute__((ext_vector_type(8))) short bf16x8;
typedef __attribute__((ext_vector_type(4))) float f32x4;

__device__ __forceinline__ f32x4 mfma_bf16(bf16x8 a, bf16x8 b, f32x4 c){
  return __builtin_amdgcn_mfma_f32_16x16x32_bf16(a, b, c, 0, 0, 0);
}
__device__ __forceinline__ float fsigm(float x){ return 1.f/(1.f+__expf(-x)); }
__device__ __forceinline__ float ftanh(float x){ return 1.f - 2.f/(__expf(2.f*x)+1.f); }
__device__ __forceinline__ unsigned short f2bf(float f){
  unsigned u = __float_as_uint(f);
  return (unsigned short)((u + 0x7fffu + ((u>>16)&1u)) >> 16);
}
__device__ __forceinline__ float bf2f(unsigned short h){
  return __uint_as_float(((unsigned)h) << 16);
}

// ================= CSR build: bucketed counting sort =================
__global__ void k_zero(int* a, int sz){
  int i = blockIdx.x*256 + threadIdx.x;
  if (i < sz) a[i] = 0;
}

// count edges (incl self loops) per 128-node bucket via LDS histogram
__global__ __launch_bounds__(256) void k_bcount(const int* __restrict__ ei, int e, int n,
                                                int nb, int* __restrict__ bcnt){
  __shared__ int h[1024];
  int t = threadIdx.x;
  for (int i = t; i < nb; i += 256) h[i] = 0;
  __syncthreads();
  int tot = e + n;
  int base = blockIdx.x*2048 + t;
  #pragma unroll
  for (int j = 0; j < 8; j++){
    int i = base + j*256;
    if (i < tot){
      int d = (i < e) ? ei[e + i] : (i - e);
      atomicAdd(&h[d >> BSH], 1);
    }
  }
  __syncthreads();
  for (int i = t; i < nb; i += 256){
    int v = h[i];
    if (v) atomicAdd(&bcnt[i], v);
  }
}

// exclusive scan of bucket counts (1 block)
__global__ __launch_bounds__(256) void k_bscan(const int* __restrict__ bcnt, int nb, int tot,
                                               int* __restrict__ bbase, int* __restrict__ bcur,
                                               int* __restrict__ rowptr, int n){
  __shared__ int sb[256];
  __shared__ int carry;
  int t = threadIdx.x;
  if (t == 0) carry = 0;
  __syncthreads();
  for (int c0 = 0; c0 < nb; c0 += 256){
    int v = (c0 + t < nb) ? bcnt[c0 + t] : 0;
    sb[t] = v; __syncthreads();
    for (int off = 1; off < 256; off <<= 1){
      int u = (t >= off) ? sb[t-off] : 0; __syncthreads();
      sb[t] += u; __syncthreads();
    }
    int excl = carry + sb[t] - v;
    if (c0 + t < nb){ bbase[c0 + t] = excl; bcur[c0 + t] = excl; }
    __syncthreads();
    if (t == 0) carry += sb[255];
    __syncthreads();
  }
  if (t == 0){ bbase[nb] = carry; rowptr[n] = tot; }
}

// scatter packed edges into bucket-contiguous regions: src in bits 0..19, local dst in 20..26
__global__ __launch_bounds__(256) void k_bscatter(const int* __restrict__ ei, int e, int n,
                                                  int* __restrict__ bcur, unsigned* __restrict__ bedges){
  int i = blockIdx.x*256 + threadIdx.x;
  if (i >= e + n) return;
  int s, d;
  if (i < e){ s = ei[i]; d = ei[e + i]; } else { s = i - e; d = s; }
  int b = d >> BSH;
  int pos = atomicAdd(&bcur[b], 1);
  bedges[pos] = (unsigned)s | ((unsigned)(d & (BNODES-1)) << 20);
}

// per-bucket: LDS hist + scan -> rowptr; then local scatter -> col (contiguous region)
__global__ __launch_bounds__(256) void k_bbuild(const unsigned* __restrict__ bedges,
                                                const int* __restrict__ bbase,
                                                int* __restrict__ rowptr, int* __restrict__ col, int n){
  int b = blockIdx.x;
  int t = threadIdx.x;
  __shared__ int hist[BNODES];
  __shared__ int sc[BNODES];
  __shared__ int cur[BNODES];
  int beg = bbase[b], end = bbase[b+1];
  if (t < BNODES) hist[t] = 0;
  __syncthreads();
  for (int i = beg + t; i < end; i += 256)
    atomicAdd(&hist[bedges[i] >> 20], 1);
  __syncthreads();
  int v = (t < BNODES) ? hist[t] : 0;
  if (t < BNODES) sc[t] = v;
  __syncthreads();
  for (int off = 1; off < BNODES; off <<= 1){
    int u = (t >= off && t < BNODES) ? sc[t-off] : 0;
    __syncthreads();
    if (t < BNODES) sc[t] += u;
    __syncthreads();
  }
  if (t < BNODES){
    int excl = sc[t] - v;
    int node = (b << BSH) + t;
    if (node < n) rowptr[node] = beg + excl;
    cur[t] = excl;
  }
  __syncthreads();
  for (int i = beg + t; i < end; i += 256){
    unsigned pk = bedges[i];
    int pos = atomicAdd(&cur[pk >> 20], 1);
    col[beg + pos] = (int)(pk & 0xFFFFFu);
  }
}

// ================= weight prep =================
template<int K>
__global__ void k_cvt_wT(const float* __restrict__ W, unsigned short* __restrict__ WT){
  int i = blockIdx.x*256 + threadIdx.x;
  if (i < 64*K){
    int k = i >> 6, c = i & 63;
    WT[c*K + k] = f2bf(W[i]);
  }
}
__global__ void k_cvt(const float* __restrict__ W, unsigned short* __restrict__ O, int sz){
  int i = blockIdx.x*256 + threadIdx.x;
  if (i < sz) O[i] = f2bf(W[i]);
}

// ================= MFMA GEMM: H[n,64] = X[n,K] @ W[K,64] =================
template<int K, bool SRCF32>
__global__ __launch_bounds__(256) void k_mf_gemm(
    const float* __restrict__ Xf, const unsigned short* __restrict__ Xh,
    const unsigned short* __restrict__ WT, unsigned short* __restrict__ Hb, int n)
{
  int t = threadIdx.x;
  int w = t >> 6, l = t & 63;
  int c = l & 15, kg = l >> 4;
  int n0 = blockIdx.x*64 + w*16;
  int row = min(n0 + c, n-1);
  f32x4 acc[4];
  #pragma unroll
  for (int j = 0; j < 4; j++) acc[j] = (f32x4){0.f,0.f,0.f,0.f};

  #pragma unroll 4
  for (int kt = 0; kt < K/32; ++kt){
    int ko = kt*32 + kg*8;
    bf16x8 a;
    if (SRCF32){
      const float* xp = Xf + (size_t)row*K + ko;
      float4 u0 = *reinterpret_cast<const float4*>(xp);
      float4 u1 = *reinterpret_cast<const float4*>(xp + 4);
      a[0]=(short)f2bf(u0.x); a[1]=(short)f2bf(u0.y); a[2]=(short)f2bf(u0.z); a[3]=(short)f2bf(u0.w);
      a[4]=(short)f2bf(u1.x); a[5]=(short)f2bf(u1.y); a[6]=(short)f2bf(u1.z); a[7]=(short)f2bf(u1.w);
    } else {
      a = *reinterpret_cast<const bf16x8*>(Xh + (size_t)row*K + ko);
    }
    #pragma unroll
    for (int j = 0; j < 4; j++){
      bf16x8 b = *reinterpret_cast<const bf16x8*>(WT + (size_t)(j*16 + c)*K + ko);
      acc[j] = mfma_bf16(a, b, acc[j]);
    }
  }
  #pragma unroll
  for (int j = 0; j < 4; j++){
    #pragma unroll
    for (int r = 0; r < 4; r++){
      int grow = n0 + kg*4 + r;
      if (grow < n) Hb[(size_t)grow*64 + j*16 + c] = f2bf(acc[j][r]);
    }
  }
}

// ================= attention logits from bf16 H =================
__global__ void k_att(const unsigned short* __restrict__ Hb,
                      const float* __restrict__ as_, const float* __restrict__ ad_,
                      float* __restrict__ als, float* __restrict__ ald, int n){
  int i = blockIdx.x*256 + threadIdx.x;   // i = node*8 + head
  if (i >= n*8) return;
  int head = i & 7;
  uint4 pk = *reinterpret_cast<const uint4*>(Hb + (size_t)i*8);
  float h[8];
  h[0]=bf2f((unsigned short)pk.x); h[1]=bf2f((unsigned short)(pk.x>>16));
  h[2]=bf2f((unsigned short)pk.y); h[3]=bf2f((unsigned short)(pk.y>>16));
  h[4]=bf2f((unsigned short)pk.z); h[5]=bf2f((unsigned short)(pk.z>>16));
  h[6]=bf2f((unsigned short)pk.w); h[7]=bf2f((unsigned short)(pk.w>>16));
  float sv = 0.f, dv = 0.f;
  #pragma unroll
  for (int j = 0; j < 8; j++){
    sv = fmaf(h[j], as_[head*8+j], sv);
    dv = fmaf(h[j], ad_[head*8+j], dv);
  }
  als[i] = sv; ald[i] = dv;
}

// ================= GAT aggregation =================
template<bool DO_ELU>
__global__ __launch_bounds__(256) void k_agg(
    const int* __restrict__ rowptr, const int* __restrict__ col,
    const unsigned short* __restrict__ Hb, const float* __restrict__ als,
    const float* __restrict__ ald, const float* __restrict__ bias,
    unsigned short* __restrict__ outb, int n)
{
  int wid = threadIdx.x >> 6, lane = threadIdx.x & 63;
  int node = blockIdx.x*4 + wid;
  if (node >= n) return;
  int hh = lane >> 3;
  float adv = ald[node*8 + hh];
  int beg = rowptr[node], end = rowptr[node+1];
  const unsigned short* Hp = Hb + lane;
  const float* ap = als + hh;

  float ssum = 0.f, acc = 0.f;
  int p = beg;
  int s0 = col[p];
  int s1 = (p+1 < end) ? col[p+1] : s0;
  int s2 = (p+2 < end) ? col[p+2] : s0;
  int s3 = (p+3 < end) ? col[p+3] : s0;
  float a0 = ap[s0*8], a1 = ap[s1*8], a2 = ap[s2*8], a3 = ap[s3*8];
  unsigned short h0 = Hp[s0*64], h1 = Hp[s1*64], h2 = Hp[s2*64], h3 = Hp[s3*64];

  while (p < end){
    int np = p + 4;
    float b0=a0, b1=a1, b2=a2, b3=a3;
    unsigned short g0=h0, g1=h1, g2=h2, g3=h3;
    if (np < end){
      s0 = col[np];
      s1 = (np+1 < end) ? col[np+1] : s0;
      s2 = (np+2 < end) ? col[np+2] : s0;
      s3 = (np+3 < end) ? col[np+3] : s0;
      a0 = ap[s0*8]; a1 = ap[s1*8]; a2 = ap[s2*8]; a3 = ap[s3*8];
      h0 = Hp[s0*64]; h1 = Hp[s1*64]; h2 = Hp[s2*64]; h3 = Hp[s3*64];
    }
    float e0 = b0 + adv; e0 = (e0>0.f)?e0:0.2f*e0;
    float e1 = b1 + adv; e1 = (e1>0.f)?e1:0.2f*e1;
    float e2 = b2 + adv; e2 = (e2>0.f)?e2:0.2f*e2;
    float e3 = b3 + adv; e3 = (e3>0.f)?e3:0.2f*e3;
    float x0 = __expf(e0);
    float x1 = (p+1 < end) ? __expf(e1) : 0.f;
    float x2 = (p+2 < end) ? __expf(e2) : 0.f;
    float x3 = (p+3 < end) ? __expf(e3) : 0.f;
    ssum += (x0 + x1) + (x2 + x3);
    acc = fmaf(x0, bf2f(g0), acc);
    acc = fmaf(x1, bf2f(g1), acc);
    acc = fmaf(x2, bf2f(g2), acc);
    acc = fmaf(x3, bf2f(g3), acc);
    p = np;
  }
  float o = acc/ssum + bias[lane];
  if (DO_ELU) o = (o > 0.f) ? o : (__expf(o) - 1.f);
  outb[(size_t)node*64 + lane] = f2bf(o);
}

// ================= LSTM step 0 =================
__global__ __launch_bounds__(256) void k_lstm0(
    const unsigned short* __restrict__ X1b, const unsigned short* __restrict__ X2b,
    const unsigned short* __restrict__ Wfx, const unsigned short* __restrict__ Wbx,
    const float* __restrict__ bihf, const float* __restrict__ bhhf,
    const float* __restrict__ bihb, const float* __restrict__ bhhb,
    const float* __restrict__ watt,
    unsigned short* __restrict__ Hf0, unsigned short* __restrict__ Cf0,
    unsigned short* __restrict__ Hb0, unsigned short* __restrict__ Cb0,
    float* __restrict__ pf0, float* __restrict__ pb0, int n)
{
  int dir = blockIdx.y;
  const unsigned short* X = dir ? X2b : X1b;
  const unsigned short* W = dir ? Wbx : Wfx;
  const float* bi = dir ? bihb : bihf;
  const float* bh = dir ? bhhb : bhhf;
  const float* wa = watt + dir*64;
  unsigned short* Ho = dir ? Hb0 : Hf0;
  unsigned short* Co = dir ? Cb0 : Cf0;
  float* po = dir ? pb0 : pf0;

  int t = threadIdx.x;
  int w = t >> 6, l = t & 63;
  int c = l & 15, kg = l >> 4;
  int n0 = blockIdx.x*32;
  int r0 = min(n0 + c, n-1);
  int r1 = min(n0 + 16 + c, n-1);
  f32x4 acc[2][4];
  #pragma unroll
  for (int m = 0; m < 2; m++)
    #pragma unroll
    for (int g = 0; g < 4; g++) acc[m][g] = (f32x4){0.f,0.f,0.f,0.f};

  #pragma unroll
  for (int kt = 0; kt < 2; ++kt){
    int ko = kt*32 + kg*8;
    bf16x8 a0 = *reinterpret_cast<const bf16x8*>(X + (size_t)r0*64 + ko);
    bf16x8 a1 = *reinterpret_cast<const bf16x8*>(X + (size_t)r1*64 + ko);
    #pragma unroll
    for (int g = 0; g < 4; g++){
      bf16x8 b = *reinterpret_cast<const bf16x8*>(W + (size_t)(g*64 + w*16 + c)*64 + ko);
      acc[0][g] = mfma_bf16(a0, b, acc[0][g]);
      acc[1][g] = mfma_bf16(a1, b, acc[1][g]);
    }
  }
  int hid = w*16 + c;
  float bs0 = bi[hid]       + bh[hid];
  float bs2 = bi[hid + 128] + bh[hid + 128];
  float bs3 = bi[hid + 192] + bh[hid + 192];
  float wav = wa[hid];
  __shared__ float attp[4][32];
  #pragma unroll
  for (int m = 0; m < 2; m++){
    #pragma unroll
    for (int r = 0; r < 4; r++){
      int rl = m*16 + kg*4 + r;
      int grow = n0 + rl;
      float gi = acc[m][0][r] + bs0;
      float gg = acc[m][2][r] + bs2;
      float go = acc[m][3][r] + bs3;
      float cc = fsigm(gi)*ftanh(gg);
      float hh = fsigm(go)*ftanh(cc);
      if (grow < n){
        Ho[(size_t)grow*64 + hid] = f2bf(hh);
        Co[(size_t)grow*64 + hid] = f2bf(cc);
      }
      float s = hh*wav;
      s += __shfl_xor(s, 1, 16);
      s += __shfl_xor(s, 2, 16);
      s += __shfl_xor(s, 4, 16);
      s += __shfl_xor(s, 8, 16);
      if (c == 0) attp[w][rl] = s;
    }
  }
  __syncthreads();
  if (t < 32){
    int grow = n0 + t;
    if (grow < n) po[grow] = attp[0][t] + attp[1][t] + attp[2][t] + attp[3][t];
  }
}

// ================= LSTM step 1 =================
__global__ __launch_bounds__(256) void k_lstm1(
    const unsigned short* __restrict__ X1b, const unsigned short* __restrict__ X2b,
    const unsigned short* __restrict__ Hf0, const unsigned short* __restrict__ Cf0,
    const unsigned short* __restrict__ Hb0, const unsigned short* __restrict__ Cb0,
    const unsigned short* __restrict__ Wfx, const unsigned short* __restrict__ Wfh,
    const unsigned short* __restrict__ Wbx, const unsigned short* __restrict__ Wbh,
    const float* __restrict__ bihf, const float* __restrict__ bhhf,
    const float* __restrict__ bihb, const float* __restrict__ bhhb,
    const float* __restrict__ watt,
    float* __restrict__ pf1, float* __restrict__ pb1, int n)
{
  int dir = blockIdx.y;
  const unsigned short* X  = dir ? X1b : X2b;
  const unsigned short* Hp = dir ? Hb0 : Hf0;
  const unsigned short* Cp = dir ? Cb0 : Cf0;
  const unsigned short* Wx = dir ? Wbx : Wfx;
  const unsigned short* Wh = dir ? Wbh : Wfh;
  const float* bi = dir ? bihb : bihf;
  const float* bh = dir ? bhhb : bhhf;
  const float* wa = watt + dir*64;
  float* po = dir ? pb1 : pf1;

  int t = threadIdx.x;
  int w = t >> 6, l = t & 63;
  int c = l & 15, kg = l >> 4;
  int n0 = blockIdx.x*32;
  int r0 = min(n0 + c, n-1);
  int r1 = min(n0 + 16 + c, n-1);
  f32x4 acc[2][4];
  #pragma unroll
  for (int m = 0; m < 2; m++)
    #pragma unroll
    for (int g = 0; g < 4; g++) acc[m][g] = (f32x4){0.f,0.f,0.f,0.f};

  #pragma unroll
  for (int kt = 0; kt < 4; ++kt){
    const unsigned short* A = (kt < 2) ? X : Hp;
    const unsigned short* Wp = (kt < 2) ? Wx : Wh;
    int ko = (kt & 1)*32 + kg*8;
    bf16x8 a0 = *reinterpret_cast<const bf16x8*>(A + (size_t)r0*64 + ko);
    bf16x8 a1 = *reinterpret_cast<const bf16x8*>(A + (size_t)r1*64 + ko);
    #pragma unroll
    for (int g = 0; g < 4; g++){
      bf16x8 b = *reinterpret_cast<const bf16x8*>(Wp + (size_t)(g*64 + w*16 + c)*64 + ko);
      acc[0][g] = mfma_bf16(a0, b, acc[0][g]);
      acc[1][g] = mfma_bf16(a1, b, acc[1][g]);
    }
  }
  int hid = w*16 + c;
  float bs0 = bi[hid]       + bh[hid];
  float bs1 = bi[hid + 64]  + bh[hid + 64];
  float bs2 = bi[hid + 128] + bh[hid + 128];
  float bs3 = bi[hid + 192] + bh[hid + 192];
  float wav = wa[hid];
  __shared__ float attp[4][32];
  #pragma unroll
  for (int m = 0; m < 2; m++){
    #pragma unroll
    for (int r = 0; r < 4; r++){
      int rl = m*16 + kg*4 + r;
      int grow = n0 + rl;
      int crow = min(grow, n-1);
      float gi = acc[m][0][r] + bs0;
      float gf = acc[m][1][r] + bs1;
      float gg = acc[m][2][r] + bs2;
      float go = acc[m][3][r] + bs3;
      float cp = bf2f(Cp[(size_t)crow*64 + hid]);
      float cc = fsigm(gf)*cp + fsigm(gi)*ftanh(gg);
      float hh = fsigm(go)*ftanh(cc);
      float s = hh*wav;
      s += __shfl_xor(s, 1, 16);
      s += __shfl_xor(s, 2, 16);
      s += __shfl_xor(s, 4, 16);
      s += __shfl_xor(s, 8, 16);
      if (c == 0) attp[w][rl] = s;
    }
  }
  __syncthreads();
  if (t < 32){
    int grow = n0 + t;
    if (grow < n) po[grow] = attp[0][t] + attp[1][t] + attp[2][t] + attp[3][t];
  }
}

// ================= JK attention + output GEMM + log_softmax =================
__global__ __launch_bounds__(256) void k_final(
    const unsigned short* __restrict__ x1b, const unsigned short* __restrict__ x2b,
    const float* __restrict__ pf0, const float* __restrict__ pf1,
    const float* __restrict__ pb0, const float* __restrict__ pb1,
    const float* __restrict__ Wout, float* __restrict__ out, int n)
{
  __shared__ __align__(16) float ws[NCLS][68];
  __shared__ __align__(16) float fs[32][68];
  int t = threadIdx.x;
  for (int i = t; i < NCLS*64; i += 256)
    ws[i>>6][i&63] = Wout[i];

  int n0 = blockIdx.x*32;
  int nd = t >> 3, q8 = t & 7;
  int g = n0 + nd;
  int eb = q8*8;
  if (g < n){
    float att0 = pf0[g] + pb1[g];
    float att1 = pf1[g] + pb0[g];
    float a0 = 1.f/(1.f + __expf(att1 - att0));
    float a1 = 1.f - a0;
    uint4 p1 = *reinterpret_cast<const uint4*>(x1b + (size_t)g*64 + eb);
    uint4 p2 = *reinterpret_cast<const uint4*>(x2b + (size_t)g*64 + eb);
    const unsigned* u1 = (const unsigned*)&p1;
    const unsigned* u2 = (const unsigned*)&p2;
    #pragma unroll
    for (int q = 0; q < 4; q++){
      float v1l = bf2f((unsigned short)u1[q]), v1h = bf2f((unsigned short)(u1[q]>>16));
      float v2l = bf2f((unsigned short)u2[q]), v2h = bf2f((unsigned short)(u2[q]>>16));
      fs[nd][eb + q*2 + 0] = a0*v1l + a1*v2l;
      fs[nd][eb + q*2 + 1] = a0*v1h + a1*v2h;
    }
  } else {
    #pragma unroll
    for (int q = 0; q < 8; q++) fs[nd][eb+q] = 0.f;
  }
  __syncthreads();

  float lg[5] = {0.f,0.f,0.f,0.f,0.f};
  #pragma unroll
  for (int k4 = 0; k4 < 16; k4++){
    float4 f = *reinterpret_cast<const float4*>(&fs[nd][k4*4]);
    #pragma unroll
    for (int q = 0; q < 5; q++){
      int cc = q8 + 8*q;
      float4 wv = *reinterpret_cast<const float4*>(&ws[cc][k4*4]);
      lg[q] = fmaf(f.x, wv.x, lg[q]);
      lg[q] = fmaf(f.y, wv.y, lg[q]);
      lg[q] = fmaf(f.z, wv.z, lg[q]);
      lg[q] = fmaf(f.w, wv.w, lg[q]);
    }
  }
  float mx = lg[0];
  #pragma unroll
  for (int q = 1; q < 5; q++) mx = fmaxf(mx, lg[q]);
  #pragma unroll
  for (int mk = 1; mk < 8; mk <<= 1) mx = fmaxf(mx, __shfl_xor(mx, mk, 64));
  float se = 0.f;
  #pragma unroll
  for (int q = 0; q < 5; q++) se += __expf(lg[q] - mx);
  #pragma unroll
  for (int mk = 1; mk < 8; mk <<= 1) se += __shfl_xor(se, mk, 64);
  float lse = __logf(se);
  if (g < n){
    #pragma unroll
    for (int q = 0; q < 5; q++)
      out[(size_t)g*NCLS + q8 + 8*q] = lg[q] - mx - lse;
  }
}

// ================= host =================
extern "C" void kernel_launch(void* const* d_in, const int* in_sizes, int n_in,
                              void* d_out, int out_size, void* d_ws, size_t ws_size,
                              hipStream_t stream)
{
  const float* x    = (const float*)d_in[0];
  const int*   ei   = (const int*)d_in[1];
  const float* W1   = (const float*)d_in[2];
  const float* a1s  = (const float*)d_in[3];
  const float* a1d  = (const float*)d_in[4];
  const float* b1   = (const float*)d_in[5];
  const float* W2   = (const float*)d_in[6];
  const float* a2s  = (const float*)d_in[7];
  const float* a2d  = (const float*)d_in[8];
  const float* b2   = (const float*)d_in[9];
  const float* Wih_f= (const float*)d_in[10];
  const float* Whh_f= (const float*)d_in[11];
  const float* bih_f= (const float*)d_in[12];
  const float* bhh_f= (const float*)d_in[13];
  const float* Wih_b= (const float*)d_in[14];
  const float* Whh_b= (const float*)d_in[15];
  const float* bih_b= (const float*)d_in[16];
  const float* bhh_b= (const float*)d_in[17];
  const float* watt = (const float*)d_in[18];
  const float* Wout = (const float*)d_in[20];
  float* out = (float*)d_out;

  int n = in_sizes[0] / F_IN;   // 100000
  int e = in_sizes[1] / 2;      // 1600000
  int nb = (n + BNODES - 1) >> BSH;   // buckets of 128 nodes

  char* p = (char*)d_ws;
  auto alloc = [&](size_t b)->char*{ char* r = p; p += (b + 255) & ~(size_t)255; return r; };
  int* rowptr = (int*)alloc((size_t)(n+1)*4);
  int* colidx = (int*)alloc((size_t)(e+n)*4);
  unsigned* bedges = (unsigned*)alloc((size_t)(e+n)*4);
  int* bcnt   = (int*)alloc((size_t)(nb+1)*4);
  int* bbase  = (int*)alloc((size_t)(nb+1)*4);
  int* bcur   = (int*)alloc((size_t)nb*4);
  unsigned short* hbuf = (unsigned short*)alloc((size_t)n*64*2);   // bf16 H
  float* als  = (float*)alloc((size_t)n*8*4);
  float* ald  = (float*)alloc((size_t)n*8*4);
  unsigned short* x1b = (unsigned short*)alloc((size_t)n*64*2);
  unsigned short* x2b = (unsigned short*)alloc((size_t)n*64*2);
  unsigned short* hf0 = (unsigned short*)alloc((size_t)n*64*2);
  unsigned short* cf0 = (unsigned short*)alloc((size_t)n*64*2);
  unsigned short* hb0 = (unsigned short*)alloc((size_t)n*64*2);
  unsigned short* cb0 = (unsigned short*)alloc((size_t)n*64*2);
  float* pf0 = (float*)alloc((size_t)n*4);
  float* pf1 = (float*)alloc((size_t)n*4);
  float* pb0 = (float*)alloc((size_t)n*4);
  float* pb1 = (float*)alloc((size_t)n*4);
  unsigned short* W1T = (unsigned short*)alloc((size_t)64*512*2);
  unsigned short* W2T = (unsigned short*)alloc((size_t)64*64*2);
  unsigned short* Wfx = (unsigned short*)alloc((size_t)256*64*2);
  unsigned short* Wfh = (unsigned short*)alloc((size_t)256*64*2);
  unsigned short* Wbx = (unsigned short*)alloc((size_t)256*64*2);
  unsigned short* Wbh = (unsigned short*)alloc((size_t)256*64*2);

  // ---- CSR build (bucketed counting sort) ----
  k_zero<<<(nb+256)/256, 256, 0, stream>>>(bcnt, nb+1);
  k_bcount<<<(e+n+2047)/2048, 256, 0, stream>>>(ei, e, n, nb, bcnt);
  k_bscan<<<1, 256, 0, stream>>>(bcnt, nb, e+n, bbase, bcur, rowptr, n);
  k_bscatter<<<(e+n+255)/256, 256, 0, stream>>>(ei, e, n, bcur, bedges);
  k_bbuild<<<nb, 256, 0, stream>>>(bedges, bbase, rowptr, colidx, n);

  // ---- weight conversion ----
  k_cvt_wT<512><<<128, 256, 0, stream>>>(W1, W1T);
  k_cvt_wT<64 ><<<16,  256, 0, stream>>>(W2, W2T);
  k_cvt<<<64, 256, 0, stream>>>(Wih_f, Wfx, 16384);
  k_cvt<<<64, 256, 0, stream>>>(Whh_f, Wfh, 16384);
  k_cvt<<<64, 256, 0, stream>>>(Wih_b, Wbx, 16384);
  k_cvt<<<64, 256, 0, stream>>>(Whh_b, Wbh, 16384);

  // ---- GAT layers ----
  int gblk = (n + 63)/64;
  k_mf_gemm<512,true ><<<gblk, 256, 0, stream>>>(x, nullptr, W1T, hbuf, n);
  k_att<<<(n*8+255)/256, 256, 0, stream>>>(hbuf, a1s, a1d, als, ald, n);
  k_agg<true ><<<(n+3)/4, 256, 0, stream>>>(rowptr, colidx, hbuf, als, ald, b1, x1b, n);
  k_mf_gemm<64,false ><<<gblk, 256, 0, stream>>>(nullptr, x1b, W2T, hbuf, n);
  k_att<<<(n*8+255)/256, 256, 0, stream>>>(hbuf, a2s, a2d, als, ald, n);
  k_agg<false><<<(n+3)/4, 256, 0, stream>>>(rowptr, colidx, hbuf, als, ald, b2, x2b, n);

  // ---- JK LSTM (both directions fused via grid.y) ----
  dim3 lgrid((n + 31)/32, 2);
  k_lstm0<<<lgrid, 256, 0, stream>>>(x1b, x2b, Wfx, Wbx, bih_f, bhh_f, bih_b, bhh_b,
                                     watt, hf0, cf0, hb0, cb0, pf0, pb0, n);
  k_lstm1<<<lgrid, 256, 0, stream>>>(x1b, x2b, hf0, cf0, hb0, cb0,
                                     Wfx, Wfh, Wbx, Wbh, bih_f, bhh_f, bih_b, bhh_b,
                                     watt, pf1, pb1, n);

  // ---- output layer ----
  k_final<<<(n+3)/4, 256, 0, stream>>>(x1b, x2b, pf0, pf1, pb0, pb1, Wout, out, n);
}

// Round 6
// 637.670 us; speedup vs baseline: 1.5720x; 1.5720x over previous
//
#include <hip/hip_runtime.h>
#include <math.h>

#define F_IN 512
#define NCLS 40
#define BSH 7                 // 128 nodes per bucket
#define BNODES (1 << BSH)
#define CH 16384              // edges per partition block

typedef __attribute__((ext_vector_type(8))) short bf16x8;
typedef __attribute__((ext_vector_type(4))) float f32x4;

__device__ __forceinline__ f32x4 mfma_bf16(bf16x8 a, bf16x8 b, f32x4 c){
  return __builtin_amdgcn_mfma_f32_16x16x32_bf16(a, b, c, 0, 0, 0);
}
__device__ __forceinline__ float fsigm(float x){ return 1.f/(1.f+__expf(-x)); }
__device__ __forceinline__ float ftanh(float x){ return 1.f - 2.f/(__expf(2.f*x)+1.f); }
__device__ __forceinline__ unsigned short f2bf(float f){
  unsigned u = __float_as_uint(f);
  return (unsigned short)((u + 0x7fffu + ((u>>16)&1u)) >> 16);
}
__device__ __forceinline__ float bf2f(unsigned short h){
  return __uint_as_float(((unsigned)h) << 16);
}

// ================= CSR build: block-aggregated partition (no global atomics) ========
// Phase A: per-chunk bucket histogram -> bhist[block][bucket]
__global__ __launch_bounds__(256) void k_pcount(const int* __restrict__ ei, int e, int n,
                                                int nb, int* __restrict__ bhist){
  __shared__ int h[1024];
  int b = blockIdx.x, t = threadIdx.x;
  for (int i = t; i < nb; i += 256) h[i] = 0;
  __syncthreads();
  int tot = e + n;
  int base = b*CH;
  int lim = min(base + CH, tot);
  for (int i = base + t; i < lim; i += 256){
    int d = (i < e) ? ei[e + i] : (i - e);
    atomicAdd(&h[d >> BSH], 1);
  }
  __syncthreads();
  for (int i = t; i < nb; i += 256) bhist[(size_t)b*nb + i] = h[i];
}

// Phase B1: per-bucket serial scan over blocks; bhist becomes intra-bucket block prefix
__global__ __launch_bounds__(256) void k_pscan1(int* __restrict__ bhist, int nb, int B,
                                                int* __restrict__ bcnt){
  int i = blockIdx.x*256 + threadIdx.x;
  if (i >= nb) return;
  int run = 0;
  for (int b = 0; b < B; b++){
    int v = bhist[(size_t)b*nb + i];
    bhist[(size_t)b*nb + i] = run;
    run += v;
  }
  bcnt[i] = run;
}

// Phase B2: exclusive scan of bucket totals (1 block)
__global__ __launch_bounds__(256) void k_pscan2(const int* __restrict__ bcnt, int nb, int tot,
                                                int* __restrict__ bbase,
                                                int* __restrict__ rowptr, int n){
  __shared__ int sb[256];
  __shared__ int carry;
  int t = threadIdx.x;
  if (t == 0) carry = 0;
  __syncthreads();
  for (int c0 = 0; c0 < nb; c0 += 256){
    int v = (c0 + t < nb) ? bcnt[c0 + t] : 0;
    sb[t] = v; __syncthreads();
    for (int off = 1; off < 256; off <<= 1){
      int u = (t >= off) ? sb[t-off] : 0; __syncthreads();
      sb[t] += u; __syncthreads();
    }
    if (c0 + t < nb) bbase[c0 + t] = carry + sb[t] - v;
    __syncthreads();
    if (t == 0) carry += sb[255];
    __syncthreads();
  }
  if (t == 0){ bbase[nb] = carry; rowptr[n] = tot; }
}

// Phase C: scatter packed edges; cursors live in LDS (base = bbase + block prefix)
__global__ __launch_bounds__(256) void k_pscatter(const int* __restrict__ ei, int e, int n,
                                                  int nb, const int* __restrict__ bhist,
                                                  const int* __restrict__ bbase,
                                                  unsigned* __restrict__ bedges){
  __shared__ int cur[1024];
  int b = blockIdx.x, t = threadIdx.x;
  for (int i = t; i < nb; i += 256)
    cur[i] = bbase[i] + bhist[(size_t)b*nb + i];
  __syncthreads();
  int tot = e + n;
  int base = b*CH;
  int lim = min(base + CH, tot);
  for (int i = base + t; i < lim; i += 256){
    int s, d;
    if (i < e){ s = ei[i]; d = ei[e + i]; } else { s = i - e; d = s; }
    int pos = atomicAdd(&cur[d >> BSH], 1);
    bedges[pos] = (unsigned)s | ((unsigned)(d & (BNODES-1)) << 20);
  }
}

// Phase D: per-bucket rowptr + col build (bucket region is contiguous, L2-resident)
__global__ __launch_bounds__(256) void k_bbuild(const unsigned* __restrict__ bedges,
                                                const int* __restrict__ bbase,
                                                int* __restrict__ rowptr, int* __restrict__ col, int n){
  int b = blockIdx.x;
  int t = threadIdx.x;
  __shared__ int hist[BNODES];
  __shared__ int sc[BNODES];
  __shared__ int cur[BNODES];
  int beg = bbase[b], end = bbase[b+1];
  if (t < BNODES) hist[t] = 0;
  __syncthreads();
  for (int i = beg + t; i < end; i += 256)
    atomicAdd(&hist[bedges[i] >> 20], 1);
  __syncthreads();
  int v = (t < BNODES) ? hist[t] : 0;
  if (t < BNODES) sc[t] = v;
  __syncthreads();
  for (int off = 1; off < BNODES; off <<= 1){
    int u = (t >= off && t < BNODES) ? sc[t-off] : 0;
    __syncthreads();
    if (t < BNODES) sc[t] += u;
    __syncthreads();
  }
  if (t < BNODES){
    int excl = sc[t] - v;
    int node = (b << BSH) + t;
    if (node < n) rowptr[node] = beg + excl;
    cur[t] = excl;
  }
  __syncthreads();
  for (int i = beg + t; i < end; i += 256){
    unsigned pk = bedges[i];
    int pos = atomicAdd(&cur[pk >> 20], 1);
    col[beg + pos] = (int)(pk & 0xFFFFFu);
  }
}

// ================= weight prep =================
template<int K>
__global__ void k_cvt_wT(const float* __restrict__ W, unsigned short* __restrict__ WT){
  int i = blockIdx.x*256 + threadIdx.x;
  if (i < 64*K){
    int k = i >> 6, c = i & 63;
    WT[c*K + k] = f2bf(W[i]);
  }
}
__global__ void k_cvt(const float* __restrict__ W, unsigned short* __restrict__ O, int sz){
  int i = blockIdx.x*256 + threadIdx.x;
  if (i < sz) O[i] = f2bf(W[i]);
}

// ================= MFMA GEMM: H[n,64] = X[n,K] @ W[K,64] =================
template<int K, bool SRCF32>
__global__ __launch_bounds__(256) void k_mf_gemm(
    const float* __restrict__ Xf, const unsigned short* __restrict__ Xh,
    const unsigned short* __restrict__ WT, unsigned short* __restrict__ Hb, int n)
{
  int t = threadIdx.x;
  int w = t >> 6, l = t & 63;
  int c = l & 15, kg = l >> 4;
  int n0 = blockIdx.x*64 + w*16;
  int row = min(n0 + c, n-1);
  f32x4 acc[4];
  #pragma unroll
  for (int j = 0; j < 4; j++) acc[j] = (f32x4){0.f,0.f,0.f,0.f};

  #pragma unroll 4
  for (int kt = 0; kt < K/32; ++kt){
    int ko = kt*32 + kg*8;
    bf16x8 a;
    if (SRCF32){
      const float* xp = Xf + (size_t)row*K + ko;
      float4 u0 = *reinterpret_cast<const float4*>(xp);
      float4 u1 = *reinterpret_cast<const float4*>(xp + 4);
      a[0]=(short)f2bf(u0.x); a[1]=(short)f2bf(u0.y); a[2]=(short)f2bf(u0.z); a[3]=(short)f2bf(u0.w);
      a[4]=(short)f2bf(u1.x); a[5]=(short)f2bf(u1.y); a[6]=(short)f2bf(u1.z); a[7]=(short)f2bf(u1.w);
    } else {
      a = *reinterpret_cast<const bf16x8*>(Xh + (size_t)row*K + ko);
    }
    #pragma unroll
    for (int j = 0; j < 4; j++){
      bf16x8 b = *reinterpret_cast<const bf16x8*>(WT + (size_t)(j*16 + c)*K + ko);
      acc[j] = mfma_bf16(a, b, acc[j]);
    }
  }
  #pragma unroll
  for (int j = 0; j < 4; j++){
    #pragma unroll
    for (int r = 0; r < 4; r++){
      int grow = n0 + kg*4 + r;
      if (grow < n) Hb[(size_t)grow*64 + j*16 + c] = f2bf(acc[j][r]);
    }
  }
}

// ================= attention logits from bf16 H =================
__global__ void k_att(const unsigned short* __restrict__ Hb,
                      const float* __restrict__ as_, const float* __restrict__ ad_,
                      float* __restrict__ als, float* __restrict__ ald, int n){
  int i = blockIdx.x*256 + threadIdx.x;   // i = node*8 + head
  if (i >= n*8) return;
  int head = i & 7;
  uint4 pk = *reinterpret_cast<const uint4*>(Hb + (size_t)i*8);
  float h[8];
  h[0]=bf2f((unsigned short)pk.x); h[1]=bf2f((unsigned short)(pk.x>>16));
  h[2]=bf2f((unsigned short)pk.y); h[3]=bf2f((unsigned short)(pk.y>>16));
  h[4]=bf2f((unsigned short)pk.z); h[5]=bf2f((unsigned short)(pk.z>>16));
  h[6]=bf2f((unsigned short)pk.w); h[7]=bf2f((unsigned short)(pk.w>>16));
  float sv = 0.f, dv = 0.f;
  #pragma unroll
  for (int j = 0; j < 8; j++){
    sv = fmaf(h[j], as_[head*8+j], sv);
    dv = fmaf(h[j], ad_[head*8+j], dv);
  }
  als[i] = sv; ald[i] = dv;
}

// ================= GAT aggregation =================
template<bool DO_ELU>
__global__ __launch_bounds__(256) void k_agg(
    const int* __restrict__ rowptr, const int* __restrict__ col,
    const unsigned short* __restrict__ Hb, const float* __restrict__ als,
    const float* __restrict__ ald, const float* __restrict__ bias,
    unsigned short* __restrict__ outb, int n)
{
  int wid = threadIdx.x >> 6, lane = threadIdx.x & 63;
  int node = blockIdx.x*4 + wid;
  if (node >= n) return;
  int hh = lane >> 3;
  float adv = ald[node*8 + hh];
  int beg = rowptr[node], end = rowptr[node+1];
  const unsigned short* Hp = Hb + lane;
  const float* ap = als + hh;

  float ssum = 0.f, acc = 0.f;
  int p = beg;
  int s0 = col[p];
  int s1 = (p+1 < end) ? col[p+1] : s0;
  int s2 = (p+2 < end) ? col[p+2] : s0;
  int s3 = (p+3 < end) ? col[p+3] : s0;
  float a0 = ap[s0*8], a1 = ap[s1*8], a2 = ap[s2*8], a3 = ap[s3*8];
  unsigned short h0 = Hp[s0*64], h1 = Hp[s1*64], h2 = Hp[s2*64], h3 = Hp[s3*64];

  while (p < end){
    int np = p + 4;
    float b0=a0, b1=a1, b2=a2, b3=a3;
    unsigned short g0=h0, g1=h1, g2=h2, g3=h3;
    if (np < end){
      s0 = col[np];
      s1 = (np+1 < end) ? col[np+1] : s0;
      s2 = (np+2 < end) ? col[np+2] : s0;
      s3 = (np+3 < end) ? col[np+3] : s0;
      a0 = ap[s0*8]; a1 = ap[s1*8]; a2 = ap[s2*8]; a3 = ap[s3*8];
      h0 = Hp[s0*64]; h1 = Hp[s1*64]; h2 = Hp[s2*64]; h3 = Hp[s3*64];
    }
    float e0 = b0 + adv; e0 = (e0>0.f)?e0:0.2f*e0;
    float e1 = b1 + adv; e1 = (e1>0.f)?e1:0.2f*e1;
    float e2 = b2 + adv; e2 = (e2>0.f)?e2:0.2f*e2;
    float e3 = b3 + adv; e3 = (e3>0.f)?e3:0.2f*e3;
    float x0 = __expf(e0);
    float x1 = (p+1 < end) ? __expf(e1) : 0.f;
    float x2 = (p+2 < end) ? __expf(e2) : 0.f;
    float x3 = (p+3 < end) ? __expf(e3) : 0.f;
    ssum += (x0 + x1) + (x2 + x3);
    acc = fmaf(x0, bf2f(g0), acc);
    acc = fmaf(x1, bf2f(g1), acc);
    acc = fmaf(x2, bf2f(g2), acc);
    acc = fmaf(x3, bf2f(g3), acc);
    p = np;
  }
  float o = acc/ssum + bias[lane];
  if (DO_ELU) o = (o > 0.f) ? o : (__expf(o) - 1.f);
  outb[(size_t)node*64 + lane] = f2bf(o);
}

// ================= LSTM step 0 =================
__global__ __launch_bounds__(256) void k_lstm0(
    const unsigned short* __restrict__ X1b, const unsigned short* __restrict__ X2b,
    const unsigned short* __restrict__ Wfx, const unsigned short* __restrict__ Wbx,
    const float* __restrict__ bihf, const float* __restrict__ bhhf,
    const float* __restrict__ bihb, const float* __restrict__ bhhb,
    const float* __restrict__ watt,
    unsigned short* __restrict__ Hf0, unsigned short* __restrict__ Cf0,
    unsigned short* __restrict__ Hb0, unsigned short* __restrict__ Cb0,
    float* __restrict__ pf0, float* __restrict__ pb0, int n)
{
  int dir = blockIdx.y;
  const unsigned short* X = dir ? X2b : X1b;
  const unsigned short* W = dir ? Wbx : Wfx;
  const float* bi = dir ? bihb : bihf;
  const float* bh = dir ? bhhb : bhhf;
  const float* wa = watt + dir*64;
  unsigned short* Ho = dir ? Hb0 : Hf0;
  unsigned short* Co = dir ? Cb0 : Cf0;
  float* po = dir ? pb0 : pf0;

  int t = threadIdx.x;
  int w = t >> 6, l = t & 63;
  int c = l & 15, kg = l >> 4;
  int n0 = blockIdx.x*32;
  int r0 = min(n0 + c, n-1);
  int r1 = min(n0 + 16 + c, n-1);
  f32x4 acc[2][4];
  #pragma unroll
  for (int m = 0; m < 2; m++)
    #pragma unroll
    for (int g = 0; g < 4; g++) acc[m][g] = (f32x4){0.f,0.f,0.f,0.f};

  #pragma unroll
  for (int kt = 0; kt < 2; ++kt){
    int ko = kt*32 + kg*8;
    bf16x8 a0 = *reinterpret_cast<const bf16x8*>(X + (size_t)r0*64 + ko);
    bf16x8 a1 = *reinterpret_cast<const bf16x8*>(X + (size_t)r1*64 + ko);
    #pragma unroll
    for (int g = 0; g < 4; g++){
      bf16x8 b = *reinterpret_cast<const bf16x8*>(W + (size_t)(g*64 + w*16 + c)*64 + ko);
      acc[0][g] = mfma_bf16(a0, b, acc[0][g]);
      acc[1][g] = mfma_bf16(a1, b, acc[1][g]);
    }
  }
  int hid = w*16 + c;
  float bs0 = bi[hid]       + bh[hid];
  float bs2 = bi[hid + 128] + bh[hid + 128];
  float bs3 = bi[hid + 192] + bh[hid + 192];
  float wav = wa[hid];
  __shared__ float attp[4][32];
  #pragma unroll
  for (int m = 0; m < 2; m++){
    #pragma unroll
    for (int r = 0; r < 4; r++){
      int rl = m*16 + kg*4 + r;
      int grow = n0 + rl;
      float gi = acc[m][0][r] + bs0;
      float gg = acc[m][2][r] + bs2;
      float go = acc[m][3][r] + bs3;
      float cc = fsigm(gi)*ftanh(gg);
      float hh = fsigm(go)*ftanh(cc);
      if (grow < n){
        Ho[(size_t)grow*64 + hid] = f2bf(hh);
        Co[(size_t)grow*64 + hid] = f2bf(cc);
      }
      float s = hh*wav;
      s += __shfl_xor(s, 1, 16);
      s += __shfl_xor(s, 2, 16);
      s += __shfl_xor(s, 4, 16);
      s += __shfl_xor(s, 8, 16);
      if (c == 0) attp[w][rl] = s;
    }
  }
  __syncthreads();
  if (t < 32){
    int grow = n0 + t;
    if (grow < n) po[grow] = attp[0][t] + attp[1][t] + attp[2][t] + attp[3][t];
  }
}

// ================= LSTM step 1 =================
__global__ __launch_bounds__(256) void k_lstm1(
    const unsigned short* __restrict__ X1b, const unsigned short* __restrict__ X2b,
    const unsigned short* __restrict__ Hf0, const unsigned short* __restrict__ Cf0,
    const unsigned short* __restrict__ Hb0, const unsigned short* __restrict__ Cb0,
    const unsigned short* __restrict__ Wfx, const unsigned short* __restrict__ Wfh,
    const unsigned short* __restrict__ Wbx, const unsigned short* __restrict__ Wbh,
    const float* __restrict__ bihf, const float* __restrict__ bhhf,
    const float* __restrict__ bihb, const float* __restrict__ bhhb,
    const float* __restrict__ watt,
    float* __restrict__ pf1, float* __restrict__ pb1, int n)
{
  int dir = blockIdx.y;
  const unsigned short* X  = dir ? X1b : X2b;
  const unsigned short* Hp = dir ? Hb0 : Hf0;
  const unsigned short* Cp = dir ? Cb0 : Cf0;
  const unsigned short* Wx = dir ? Wbx : Wfx;
  const unsigned short* Wh = dir ? Wbh : Wfh;
  const float* bi = dir ? bihb : bihf;
  const float* bh = dir ? bhhb : bhhf;
  const float* wa = watt + dir*64;
  float* po = dir ? pb1 : pf1;

  int t = threadIdx.x;
  int w = t >> 6, l = t & 63;
  int c = l & 15, kg = l >> 4;
  int n0 = blockIdx.x*32;
  int r0 = min(n0 + c, n-1);
  int r1 = min(n0 + 16 + c, n-1);
  f32x4 acc[2][4];
  #pragma unroll
  for (int m = 0; m < 2; m++)
    #pragma unroll
    for (int g = 0; g < 4; g++) acc[m][g] = (f32x4){0.f,0.f,0.f,0.f};

  #pragma unroll
  for (int kt = 0; kt < 4; ++kt){
    const unsigned short* A = (kt < 2) ? X : Hp;
    const unsigned short* Wp = (kt < 2) ? Wx : Wh;
    int ko = (kt & 1)*32 + kg*8;
    bf16x8 a0 = *reinterpret_cast<const bf16x8*>(A + (size_t)r0*64 + ko);
    bf16x8 a1 = *reinterpret_cast<const bf16x8*>(A + (size_t)r1*64 + ko);
    #pragma unroll
    for (int g = 0; g < 4; g++){
      bf16x8 b = *reinterpret_cast<const bf16x8*>(Wp + (size_t)(g*64 + w*16 + c)*64 + ko);
      acc[0][g] = mfma_bf16(a0, b, acc[0][g]);
      acc[1][g] = mfma_bf16(a1, b, acc[1][g]);
    }
  }
  int hid = w*16 + c;
  float bs0 = bi[hid]       + bh[hid];
  float bs1 = bi[hid + 64]  + bh[hid + 64];
  float bs2 = bi[hid + 128] + bh[hid + 128];
  float bs3 = bi[hid + 192] + bh[hid + 192];
  float wav = wa[hid];
  __shared__ float attp[4][32];
  #pragma unroll
  for (int m = 0; m < 2; m++){
    #pragma unroll
    for (int r = 0; r < 4; r++){
      int rl = m*16 + kg*4 + r;
      int grow = n0 + rl;
      int crow = min(grow, n-1);
      float gi = acc[m][0][r] + bs0;
      float gf = acc[m][1][r] + bs1;
      float gg = acc[m][2][r] + bs2;
      float go = acc[m][3][r] + bs3;
      float cp = bf2f(Cp[(size_t)crow*64 + hid]);
      float cc = fsigm(gf)*cp + fsigm(gi)*ftanh(gg);
      float hh = fsigm(go)*ftanh(cc);
      float s = hh*wav;
      s += __shfl_xor(s, 1, 16);
      s += __shfl_xor(s, 2, 16);
      s += __shfl_xor(s, 4, 16);
      s += __shfl_xor(s, 8, 16);
      if (c == 0) attp[w][rl] = s;
    }
  }
  __syncthreads();
  if (t < 32){
    int grow = n0 + t;
    if (grow < n) po[grow] = attp[0][t] + attp[1][t] + attp[2][t] + attp[3][t];
  }
}

// ================= JK attention + output GEMM + log_softmax =================
__global__ __launch_bounds__(256) void k_final(
    const unsigned short* __restrict__ x1b, const unsigned short* __restrict__ x2b,
    const float* __restrict__ pf0, const float* __restrict__ pf1,
    const float* __restrict__ pb0, const float* __restrict__ pb1,
    const float* __restrict__ Wout, float* __restrict__ out, int n)
{
  __shared__ __align__(16) float ws[NCLS][68];
  __shared__ __align__(16) float fs[32][68];
  int t = threadIdx.x;
  for (int i = t; i < NCLS*64; i += 256)
    ws[i>>6][i&63] = Wout[i];

  int n0 = blockIdx.x*32;
  int nd = t >> 3, q8 = t & 7;
  int g = n0 + nd;
  int eb = q8*8;
  if (g < n){
    float att0 = pf0[g] + pb1[g];
    float att1 = pf1[g] + pb0[g];
    float a0 = 1.f/(1.f + __expf(att1 - att0));
    float a1 = 1.f - a0;
    uint4 p1 = *reinterpret_cast<const uint4*>(x1b + (size_t)g*64 + eb);
    uint4 p2 = *reinterpret_cast<const uint4*>(x2b + (size_t)g*64 + eb);
    const unsigned* u1 = (const unsigned*)&p1;
    const unsigned* u2 = (const unsigned*)&p2;
    #pragma unroll
    for (int q = 0; q < 4; q++){
      float v1l = bf2f((unsigned short)u1[q]), v1h = bf2f((unsigned short)(u1[q]>>16));
      float v2l = bf2f((unsigned short)u2[q]), v2h = bf2f((unsigned short)(u2[q]>>16));
      fs[nd][eb + q*2 + 0] = a0*v1l + a1*v2l;
      fs[nd][eb + q*2 + 1] = a0*v1h + a1*v2h;
    }
  } else {
    #pragma unroll
    for (int q = 0; q < 8; q++) fs[nd][eb+q] = 0.f;
  }
  __syncthreads();

  float lg[5] = {0.f,0.f,0.f,0.f,0.f};
  #pragma unroll
  for (int k4 = 0; k4 < 16; k4++){
    float4 f = *reinterpret_cast<const float4*>(&fs[nd][k4*4]);
    #pragma unroll
    for (int q = 0; q < 5; q++){
      int cc = q8 + 8*q;
      float4 wv = *reinterpret_cast<const float4*>(&ws[cc][k4*4]);
      lg[q] = fmaf(f.x, wv.x, lg[q]);
      lg[q] = fmaf(f.y, wv.y, lg[q]);
      lg[q] = fmaf(f.z, wv.z, lg[q]);
      lg[q] = fmaf(f.w, wv.w, lg[q]);
    }
  }
  float mx = lg[0];
  #pragma unroll
  for (int q = 1; q < 5; q++) mx = fmaxf(mx, lg[q]);
  #pragma unroll
  for (int mk = 1; mk < 8; mk <<= 1) mx = fmaxf(mx, __shfl_xor(mx, mk, 64));
  float se = 0.f;
  #pragma unroll
  for (int q = 0; q < 5; q++) se += __expf(lg[q] - mx);
  #pragma unroll
  for (int mk = 1; mk < 8; mk <<= 1) se += __shfl_xor(se, mk, 64);
  float lse = __logf(se);
  if (g < n){
    #pragma unroll
    for (int q = 0; q < 5; q++)
      out[(size_t)g*NCLS + q8 + 8*q] = lg[q] - mx - lse;
  }
}

// ================= host =================
extern "C" void kernel_launch(void* const* d_in, const int* in_sizes, int n_in,
                              void* d_out, int out_size, void* d_ws, size_t ws_size,
                              hipStream_t stream)
{
  const float* x    = (const float*)d_in[0];
  const int*   ei   = (const int*)d_in[1];
  const float* W1   = (const float*)d_in[2];
  const float* a1s  = (const float*)d_in[3];
  const float* a1d  = (const float*)d_in[4];
  const float* b1   = (const float*)d_in[5];
  const float* W2   = (const float*)d_in[6];
  const float* a2s  = (const float*)d_in[7];
  const float* a2d  = (const float*)d_in[8];
  const float* b2   = (const float*)d_in[9];
  const float* Wih_f= (const float*)d_in[10];
  const float* Whh_f= (const float*)d_in[11];
  const float* bih_f= (const float*)d_in[12];
  const float* bhh_f= (const float*)d_in[13];
  const float* Wih_b= (const float*)d_in[14];
  const float* Whh_b= (const float*)d_in[15];
  const float* bih_b= (const float*)d_in[16];
  const float* bhh_b= (const float*)d_in[17];
  const float* watt = (const float*)d_in[18];
  const float* Wout = (const float*)d_in[20];
  float* out = (float*)d_out;

  int n = in_sizes[0] / F_IN;   // 100000
  int e = in_sizes[1] / 2;      // 1600000
  int nb = (n + BNODES - 1) >> BSH;       // buckets of 128 nodes (782)
  int B  = (e + n + CH - 1) / CH;         // partition blocks (~104)

  char* p = (char*)d_ws;
  auto alloc = [&](size_t b)->char*{ char* r = p; p += (b + 255) & ~(size_t)255; return r; };
  int* rowptr = (int*)alloc((size_t)(n+1)*4);
  int* colidx = (int*)alloc((size_t)(e+n)*4);
  unsigned* bedges = (unsigned*)alloc((size_t)(e+n)*4);
  int* bhist  = (int*)alloc((size_t)B*nb*4);
  int* bcnt   = (int*)alloc((size_t)(nb+1)*4);
  int* bbase  = (int*)alloc((size_t)(nb+1)*4);
  unsigned short* hbuf = (unsigned short*)alloc((size_t)n*64*2);   // bf16 H
  float* als  = (float*)alloc((size_t)n*8*4);
  float* ald  = (float*)alloc((size_t)n*8*4);
  unsigned short* x1b = (unsigned short*)alloc((size_t)n*64*2);
  unsigned short* x2b = (unsigned short*)alloc((size_t)n*64*2);
  unsigned short* hf0 = (unsigned short*)alloc((size_t)n*64*2);
  unsigned short* cf0 = (unsigned short*)alloc((size_t)n*64*2);
  unsigned short* hb0 = (unsigned short*)alloc((size_t)n*64*2);
  unsigned short* cb0 = (unsigned short*)alloc((size_t)n*64*2);
  float* pf0 = (float*)alloc((size_t)n*4);
  float* pf1 = (float*)alloc((size_t)n*4);
  float* pb0 = (float*)alloc((size_t)n*4);
  float* pb1 = (float*)alloc((size_t)n*4);
  unsigned short* W1T = (unsigned short*)alloc((size_t)64*512*2);
  unsigned short* W2T = (unsigned short*)alloc((size_t)64*64*2);
  unsigned short* Wfx = (unsigned short*)alloc((size_t)256*64*2);
  unsigned short* Wfh = (unsigned short*)alloc((size_t)256*64*2);
  unsigned short* Wbx = (unsigned short*)alloc((size_t)256*64*2);
  unsigned short* Wbh = (unsigned short*)alloc((size_t)256*64*2);

  // ---- CSR build (block-aggregated partition, no global atomics) ----
  k_pcount<<<B, 256, 0, stream>>>(ei, e, n, nb, bhist);
  k_pscan1<<<(nb+255)/256, 256, 0, stream>>>(bhist, nb, B, bcnt);
  k_pscan2<<<1, 256, 0, stream>>>(bcnt, nb, e+n, bbase, rowptr, n);
  k_pscatter<<<B, 256, 0, stream>>>(ei, e, n, nb, bhist, bbase, bedges);
  k_bbuild<<<nb, 256, 0, stream>>>(bedges, bbase, rowptr, colidx, n);

  // ---- weight conversion ----
  k_cvt_wT<512><<<128, 256, 0, stream>>>(W1, W1T);
  k_cvt_wT<64 ><<<16,  256, 0, stream>>>(W2, W2T);
  k_cvt<<<64, 256, 0, stream>>>(Wih_f, Wfx, 16384);
  k_cvt<<<64, 256, 0, stream>>>(Whh_f, Wfh, 16384);
  k_cvt<<<64, 256, 0, stream>>>(Wih_b, Wbx, 16384);
  k_cvt<<<64, 256, 0, stream>>>(Whh_b, Wbh, 16384);

  // ---- GAT layers ----
  int gblk = (n + 63)/64;
  k_mf_gemm<512,true ><<<gblk, 256, 0, stream>>>(x, nullptr, W1T, hbuf, n);
  k_att<<<(n*8+255)/256, 256, 0, stream>>>(hbuf, a1s, a1d, als, ald, n);
  k_agg<true ><<<(n+3)/4, 256, 0, stream>>>(rowptr, colidx, hbuf, als, ald, b1, x1b, n);
  k_mf_gemm<64,false ><<<gblk, 256, 0, stream>>>(nullptr, x1b, W2T, hbuf, n);
  k_att<<<(n*8+255)/256, 256, 0, stream>>>(hbuf, a2s, a2d, als, ald, n);
  k_agg<false><<<(n+3)/4, 256, 0, stream>>>(rowptr, colidx, hbuf, als, ald, b2, x2b, n);

  // ---- JK LSTM (both directions fused via grid.y) ----
  dim3 lgrid((n + 31)/32, 2);
  k_lstm0<<<lgrid, 256, 0, stream>>>(x1b, x2b, Wfx, Wbx, bih_f, bhh_f, bih_b, bhh_b,
                                     watt, hf0, cf0, hb0, cb0, pf0, pb0, n);
  k_lstm1<<<lgrid, 256, 0, stream>>>(x1b, x2b, hf0, cf0, hb0, cb0,
                                     Wfx, Wfh, Wbx, Wbh, bih_f, bhh_f, bih_b, bhh_b,
                                     watt, pf1, pb1, n);

  // ---- output layer ----
  k_final<<<(n+3)/4, 256, 0, stream>>>(x1b, x2b, pf0, pf1, pb0, pb1, Wout, out, n);
}

// Round 7
// 562.525 us; speedup vs baseline: 1.7820x; 1.1336x over previous
//
#include <hip/hip_runtime.h>
#include <math.h>

#define F_IN 512
#define NCLS 40
#define BSH 7                 // 128 nodes per bucket
#define BNODES (1 << BSH)
#define CH 16384              // edges per partition block

typedef __attribute__((ext_vector_type(8))) short bf16x8;
typedef __attribute__((ext_vector_type(4))) float f32x4;

__device__ __forceinline__ f32x4 mfma_bf16(bf16x8 a, bf16x8 b, f32x4 c){
  return __builtin_amdgcn_mfma_f32_16x16x32_bf16(a, b, c, 0, 0, 0);
}
__device__ __forceinline__ float fsigm(float x){ return 1.f/(1.f+__expf(-x)); }
__device__ __forceinline__ float ftanh(float x){ return 1.f - 2.f/(__expf(2.f*x)+1.f); }
__device__ __forceinline__ unsigned short f2bf(float f){
  unsigned u = __float_as_uint(f);
  return (unsigned short)((u + 0x7fffu + ((u>>16)&1u)) >> 16);
}
__device__ __forceinline__ float bf2f(unsigned short h){
  return __uint_as_float(((unsigned)h) << 16);
}

// ================= CSR build: block-aggregated partition (no global atomics) ========
__global__ __launch_bounds__(256) void k_pcount(const int* __restrict__ ei, int e, int n,
                                                int nb, int* __restrict__ bhist){
  __shared__ int h[1024];
  int b = blockIdx.x, t = threadIdx.x;
  for (int i = t; i < nb; i += 256) h[i] = 0;
  __syncthreads();
  int tot = e + n;
  int base = b*CH;
  int lim = min(base + CH, tot);
  for (int i = base + t; i < lim; i += 256){
    int d = (i < e) ? ei[e + i] : (i - e);
    atomicAdd(&h[d >> BSH], 1);
  }
  __syncthreads();
  for (int i = t; i < nb; i += 256) bhist[(size_t)b*nb + i] = h[i];
}

__global__ __launch_bounds__(256) void k_pscan1(int* __restrict__ bhist, int nb, int B,
                                                int* __restrict__ bcnt){
  int i = blockIdx.x*256 + threadIdx.x;
  if (i >= nb) return;
  int run = 0;
  for (int b = 0; b < B; b++){
    int v = bhist[(size_t)b*nb + i];
    bhist[(size_t)b*nb + i] = run;
    run += v;
  }
  bcnt[i] = run;
}

__global__ __launch_bounds__(256) void k_pscan2(const int* __restrict__ bcnt, int nb, int tot,
                                                int* __restrict__ bbase,
                                                int* __restrict__ rowptr, int n){
  __shared__ int sb[256];
  __shared__ int carry;
  int t = threadIdx.x;
  if (t == 0) carry = 0;
  __syncthreads();
  for (int c0 = 0; c0 < nb; c0 += 256){
    int v = (c0 + t < nb) ? bcnt[c0 + t] : 0;
    sb[t] = v; __syncthreads();
    for (int off = 1; off < 256; off <<= 1){
      int u = (t >= off) ? sb[t-off] : 0; __syncthreads();
      sb[t] += u; __syncthreads();
    }
    if (c0 + t < nb) bbase[c0 + t] = carry + sb[t] - v;
    __syncthreads();
    if (t == 0) carry += sb[255];
    __syncthreads();
  }
  if (t == 0){ bbase[nb] = carry; rowptr[n] = tot; }
}

__global__ __launch_bounds__(256) void k_pscatter(const int* __restrict__ ei, int e, int n,
                                                  int nb, const int* __restrict__ bhist,
                                                  const int* __restrict__ bbase,
                                                  unsigned* __restrict__ bedges){
  __shared__ int cur[1024];
  int b = blockIdx.x, t = threadIdx.x;
  for (int i = t; i < nb; i += 256)
    cur[i] = bbase[i] + bhist[(size_t)b*nb + i];
  __syncthreads();
  int tot = e + n;
  int base = b*CH;
  int lim = min(base + CH, tot);
  for (int i = base + t; i < lim; i += 256){
    int s, d;
    if (i < e){ s = ei[i]; d = ei[e + i]; } else { s = i - e; d = s; }
    int pos = atomicAdd(&cur[d >> BSH], 1);
    bedges[pos] = (unsigned)s | ((unsigned)(d & (BNODES-1)) << 20);
  }
}

__global__ __launch_bounds__(256) void k_bbuild(const unsigned* __restrict__ bedges,
                                                const int* __restrict__ bbase,
                                                int* __restrict__ rowptr, int* __restrict__ col, int n){
  int b = blockIdx.x;
  int t = threadIdx.x;
  __shared__ int hist[BNODES];
  __shared__ int sc[BNODES];
  __shared__ int cur[BNODES];
  int beg = bbase[b], end = bbase[b+1];
  if (t < BNODES) hist[t] = 0;
  __syncthreads();
  for (int i = beg + t; i < end; i += 256)
    atomicAdd(&hist[bedges[i] >> 20], 1);
  __syncthreads();
  int v = (t < BNODES) ? hist[t] : 0;
  if (t < BNODES) sc[t] = v;
  __syncthreads();
  for (int off = 1; off < BNODES; off <<= 1){
    int u = (t >= off && t < BNODES) ? sc[t-off] : 0;
    __syncthreads();
    if (t < BNODES) sc[t] += u;
    __syncthreads();
  }
  if (t < BNODES){
    int excl = sc[t] - v;
    int node = (b << BSH) + t;
    if (node < n) rowptr[node] = beg + excl;
    cur[t] = excl;
  }
  __syncthreads();
  for (int i = beg + t; i < end; i += 256){
    unsigned pk = bedges[i];
    int pos = atomicAdd(&cur[pk >> 20], 1);
    col[beg + pos] = (int)(pk & 0xFFFFFu);
  }
}

// ================= fused weight prep (all conversions, 1 dispatch) =================
__global__ __launch_bounds__(256) void k_prep(
    const float* __restrict__ W1, const float* __restrict__ W2,
    const float* __restrict__ Wihf, const float* __restrict__ Whhf,
    const float* __restrict__ Wihb, const float* __restrict__ Whhb,
    unsigned short* __restrict__ W1T, unsigned short* __restrict__ W2T,
    unsigned short* __restrict__ Wfx, unsigned short* __restrict__ Wfh,
    unsigned short* __restrict__ Wbx, unsigned short* __restrict__ Wbh)
{
  int i = blockIdx.x*256 + threadIdx.x;
  if (i < 32768){                 // W1 [512][64] -> W1T [64][512]
    int k = i >> 6, c = i & 63;
    W1T[c*512 + k] = f2bf(W1[i]);
  } else if (i < 36864){          // W2 [64][64] -> W2T [64][64]
    int j = i - 32768; int k = j >> 6, c = j & 63;
    W2T[c*64 + k] = f2bf(W2[j]);
  } else if (i < 102400){         // 4 x [256][64] straight bf16 copies
    int j = i - 36864;
    int which = j >> 14, o = j & 16383;
    const float* src = which==0 ? Wihf : which==1 ? Whhf : which==2 ? Wihb : Whhb;
    unsigned short* dst = which==0 ? Wfx : which==1 ? Wfh : which==2 ? Wbx : Wbh;
    dst[o] = f2bf(src[o]);
  }
}

// ================= MFMA GEMM + fused attention-logit epilogue =================
// H[n,64] = X[n,K] @ W[K,64]; als (bf16) / ald (f32) computed in-register.
template<int K, bool SRCF32>
__global__ __launch_bounds__(256) void k_mf_gemm(
    const float* __restrict__ Xf, const unsigned short* __restrict__ Xh,
    const unsigned short* __restrict__ WT,
    const float* __restrict__ as_, const float* __restrict__ ad_,
    unsigned short* __restrict__ Hb, unsigned short* __restrict__ alsb,
    float* __restrict__ ald, int n)
{
  int t = threadIdx.x;
  int w = t >> 6, l = t & 63;
  int c = l & 15, kg = l >> 4;
  int n0 = blockIdx.x*64 + w*16;
  int row = min(n0 + c, n-1);
  f32x4 acc[4];
  #pragma unroll
  for (int j = 0; j < 4; j++) acc[j] = (f32x4){0.f,0.f,0.f,0.f};

  #pragma unroll 4
  for (int kt = 0; kt < K/32; ++kt){
    int ko = kt*32 + kg*8;
    bf16x8 a;
    if (SRCF32){
      const float* xp = Xf + (size_t)row*K + ko;
      float4 u0 = *reinterpret_cast<const float4*>(xp);
      float4 u1 = *reinterpret_cast<const float4*>(xp + 4);
      a[0]=(short)f2bf(u0.x); a[1]=(short)f2bf(u0.y); a[2]=(short)f2bf(u0.z); a[3]=(short)f2bf(u0.w);
      a[4]=(short)f2bf(u1.x); a[5]=(short)f2bf(u1.y); a[6]=(short)f2bf(u1.z); a[7]=(short)f2bf(u1.w);
    } else {
      a = *reinterpret_cast<const bf16x8*>(Xh + (size_t)row*K + ko);
    }
    #pragma unroll
    for (int j = 0; j < 4; j++){
      bf16x8 b = *reinterpret_cast<const bf16x8*>(WT + (size_t)(j*16 + c)*K + ko);
      acc[j] = mfma_bf16(a, b, acc[j]);
    }
  }
  // epilogue: store H (bf16) + per-head logits.
  // acc[j][r] = C[row = kg*4+r][col = j*16+c]; head(col) = 2j + (c>>3);
  // reduce over the 8 lanes with same c>>3 (xor 1,2,4 stays within the 16-lane group).
  float asl[4], adl[4];
  #pragma unroll
  for (int j = 0; j < 4; j++){ asl[j] = as_[j*16 + c]; adl[j] = ad_[j*16 + c]; }
  #pragma unroll
  for (int j = 0; j < 4; j++){
    #pragma unroll
    for (int r = 0; r < 4; r++){
      int grow = n0 + kg*4 + r;
      float v = acc[j][r];
      if (grow < n) Hb[(size_t)grow*64 + j*16 + c] = f2bf(v);
      float sv = v*asl[j];
      float dv = v*adl[j];
      sv += __shfl_xor(sv, 1, 64); sv += __shfl_xor(sv, 2, 64); sv += __shfl_xor(sv, 4, 64);
      dv += __shfl_xor(dv, 1, 64); dv += __shfl_xor(dv, 2, 64); dv += __shfl_xor(dv, 4, 64);
      if ((c & 7) == 0 && grow < n){
        int head = j*2 + (c >> 3);
        alsb[(size_t)grow*8 + head] = f2bf(sv);
        ald [(size_t)grow*8 + head] = dv;
      }
    }
  }
}

// ================= GAT aggregation: 2 nodes/wave, 4B H loads, bf16 als =============
template<bool DO_ELU>
__global__ __launch_bounds__(256) void k_agg(
    const int* __restrict__ rowptr, const int* __restrict__ col,
    const unsigned short* __restrict__ Hb, const unsigned short* __restrict__ alsb,
    const float* __restrict__ ald, const float* __restrict__ bias,
    unsigned short* __restrict__ outb, int n)
{
  int half = threadIdx.x >> 5;          // 8 half-waves per block
  int ln = threadIdx.x & 31;            // lane within half-wave: 2 channels
  int node = blockIdx.x*8 + half;
  if (node >= n) return;
  int hh = ln >> 2;                     // head (4 lanes per head)
  float adv = ald[node*8 + hh];
  int beg = rowptr[node], end = rowptr[node+1];
  const unsigned short* Hp = Hb + ln*2;
  const unsigned short* ap = alsb + hh;

  float ssum = 0.f, acc0 = 0.f, acc1 = 0.f;
  int p = beg;
  int s0 = col[p];
  int s1 = (p+1 < end) ? col[p+1] : s0;
  int s2 = (p+2 < end) ? col[p+2] : s0;
  int s3 = (p+3 < end) ? col[p+3] : s0;
  float a0 = bf2f(ap[s0*8]), a1 = bf2f(ap[s1*8]);
  float a2 = bf2f(ap[s2*8]), a3 = bf2f(ap[s3*8]);
  unsigned h0 = *reinterpret_cast<const unsigned*>(Hp + (size_t)s0*64);
  unsigned h1 = *reinterpret_cast<const unsigned*>(Hp + (size_t)s1*64);
  unsigned h2 = *reinterpret_cast<const unsigned*>(Hp + (size_t)s2*64);
  unsigned h3 = *reinterpret_cast<const unsigned*>(Hp + (size_t)s3*64);

  while (p < end){
    int np = p + 4;
    float b0=a0, b1=a1, b2=a2, b3=a3;
    unsigned g0=h0, g1=h1, g2=h2, g3=h3;
    if (np < end){
      s0 = col[np];
      s1 = (np+1 < end) ? col[np+1] : s0;
      s2 = (np+2 < end) ? col[np+2] : s0;
      s3 = (np+3 < end) ? col[np+3] : s0;
      a0 = bf2f(ap[s0*8]); a1 = bf2f(ap[s1*8]);
      a2 = bf2f(ap[s2*8]); a3 = bf2f(ap[s3*8]);
      h0 = *reinterpret_cast<const unsigned*>(Hp + (size_t)s0*64);
      h1 = *reinterpret_cast<const unsigned*>(Hp + (size_t)s1*64);
      h2 = *reinterpret_cast<const unsigned*>(Hp + (size_t)s2*64);
      h3 = *reinterpret_cast<const unsigned*>(Hp + (size_t)s3*64);
    }
    float e0 = b0 + adv; e0 = (e0>0.f)?e0:0.2f*e0;
    float e1 = b1 + adv; e1 = (e1>0.f)?e1:0.2f*e1;
    float e2 = b2 + adv; e2 = (e2>0.f)?e2:0.2f*e2;
    float e3 = b3 + adv; e3 = (e3>0.f)?e3:0.2f*e3;
    float x0 = __expf(e0);
    float x1 = (p+1 < end) ? __expf(e1) : 0.f;
    float x2 = (p+2 < end) ? __expf(e2) : 0.f;
    float x3 = (p+3 < end) ? __expf(e3) : 0.f;
    ssum += (x0 + x1) + (x2 + x3);
    acc0 = fmaf(x0, bf2f((unsigned short)g0), acc0);
    acc1 = fmaf(x0, bf2f((unsigned short)(g0>>16)), acc1);
    acc0 = fmaf(x1, bf2f((unsigned short)g1), acc0);
    acc1 = fmaf(x1, bf2f((unsigned short)(g1>>16)), acc1);
    acc0 = fmaf(x2, bf2f((unsigned short)g2), acc0);
    acc1 = fmaf(x2, bf2f((unsigned short)(g2>>16)), acc1);
    acc0 = fmaf(x3, bf2f((unsigned short)g3), acc0);
    acc1 = fmaf(x3, bf2f((unsigned short)(g3>>16)), acc1);
    p = np;
  }
  float inv = 1.f/ssum;
  float o0 = acc0*inv + bias[ln*2];
  float o1 = acc1*inv + bias[ln*2+1];
  if (DO_ELU){
    o0 = (o0 > 0.f) ? o0 : (__expf(o0) - 1.f);
    o1 = (o1 > 0.f) ? o1 : (__expf(o1) - 1.f);
  }
  unsigned pk = (unsigned)f2bf(o0) | ((unsigned)f2bf(o1) << 16);
  *reinterpret_cast<unsigned*>(outb + (size_t)node*64 + ln*2) = pk;
}

// ================= LSTM step 0 =================
__global__ __launch_bounds__(256) void k_lstm0(
    const unsigned short* __restrict__ X1b, const unsigned short* __restrict__ X2b,
    const unsigned short* __restrict__ Wfx, const unsigned short* __restrict__ Wbx,
    const float* __restrict__ bihf, const float* __restrict__ bhhf,
    const float* __restrict__ bihb, const float* __restrict__ bhhb,
    const float* __restrict__ watt,
    unsigned short* __restrict__ Hf0, unsigned short* __restrict__ Cf0,
    unsigned short* __restrict__ Hb0, unsigned short* __restrict__ Cb0,
    float* __restrict__ pf0, float* __restrict__ pb0, int n)
{
  int dir = blockIdx.y;
  const unsigned short* X = dir ? X2b : X1b;
  const unsigned short* W = dir ? Wbx : Wfx;
  const float* bi = dir ? bihb : bihf;
  const float* bh = dir ? bhhb : bhhf;
  const float* wa = watt + dir*64;
  unsigned short* Ho = dir ? Hb0 : Hf0;
  unsigned short* Co = dir ? Cb0 : Cf0;
  float* po = dir ? pb0 : pf0;

  int t = threadIdx.x;
  int w = t >> 6, l = t & 63;
  int c = l & 15, kg = l >> 4;
  int n0 = blockIdx.x*32;
  int r0 = min(n0 + c, n-1);
  int r1 = min(n0 + 16 + c, n-1);
  f32x4 acc[2][4];
  #pragma unroll
  for (int m = 0; m < 2; m++)
    #pragma unroll
    for (int g = 0; g < 4; g++) acc[m][g] = (f32x4){0.f,0.f,0.f,0.f};

  #pragma unroll
  for (int kt = 0; kt < 2; ++kt){
    int ko = kt*32 + kg*8;
    bf16x8 a0 = *reinterpret_cast<const bf16x8*>(X + (size_t)r0*64 + ko);
    bf16x8 a1 = *reinterpret_cast<const bf16x8*>(X + (size_t)r1*64 + ko);
    #pragma unroll
    for (int g = 0; g < 4; g++){
      bf16x8 b = *reinterpret_cast<const bf16x8*>(W + (size_t)(g*64 + w*16 + c)*64 + ko);
      acc[0][g] = mfma_bf16(a0, b, acc[0][g]);
      acc[1][g] = mfma_bf16(a1, b, acc[1][g]);
    }
  }
  int hid = w*16 + c;
  float bs0 = bi[hid]       + bh[hid];
  float bs2 = bi[hid + 128] + bh[hid + 128];
  float bs3 = bi[hid + 192] + bh[hid + 192];
  float wav = wa[hid];
  __shared__ float attp[4][32];
  #pragma unroll
  for (int m = 0; m < 2; m++){
    #pragma unroll
    for (int r = 0; r < 4; r++){
      int rl = m*16 + kg*4 + r;
      int grow = n0 + rl;
      float gi = acc[m][0][r] + bs0;
      float gg = acc[m][2][r] + bs2;
      float go = acc[m][3][r] + bs3;
      float cc = fsigm(gi)*ftanh(gg);
      float hh = fsigm(go)*ftanh(cc);
      if (grow < n){
        Ho[(size_t)grow*64 + hid] = f2bf(hh);
        Co[(size_t)grow*64 + hid] = f2bf(cc);
      }
      float s = hh*wav;
      s += __shfl_xor(s, 1, 16);
      s += __shfl_xor(s, 2, 16);
      s += __shfl_xor(s, 4, 16);
      s += __shfl_xor(s, 8, 16);
      if (c == 0) attp[w][rl] = s;
    }
  }
  __syncthreads();
  if (t < 32){
    int grow = n0 + t;
    if (grow < n) po[grow] = attp[0][t] + attp[1][t] + attp[2][t] + attp[3][t];
  }
}

// ================= LSTM step 1 =================
__global__ __launch_bounds__(256) void k_lstm1(
    const unsigned short* __restrict__ X1b, const unsigned short* __restrict__ X2b,
    const unsigned short* __restrict__ Hf0, const unsigned short* __restrict__ Cf0,
    const unsigned short* __restrict__ Hb0, const unsigned short* __restrict__ Cb0,
    const unsigned short* __restrict__ Wfx, const unsigned short* __restrict__ Wfh,
    const unsigned short* __restrict__ Wbx, const unsigned short* __restrict__ Wbh,
    const float* __restrict__ bihf, const float* __restrict__ bhhf,
    const float* __restrict__ bihb, const float* __restrict__ bhhb,
    const float* __restrict__ watt,
    float* __restrict__ pf1, float* __restrict__ pb1, int n)
{
  int dir = blockIdx.y;
  const unsigned short* X  = dir ? X1b : X2b;
  const unsigned short* Hp = dir ? Hb0 : Hf0;
  const unsigned short* Cp = dir ? Cb0 : Cf0;
  const unsigned short* Wx = dir ? Wbx : Wfx;
  const unsigned short* Wh = dir ? Wbh : Wfh;
  const float* bi = dir ? bihb : bihf;
  const float* bh = dir ? bhhb : bhhf;
  const float* wa = watt + dir*64;
  float* po = dir ? pb1 : pf1;

  int t = threadIdx.x;
  int w = t >> 6, l = t & 63;
  int c = l & 15, kg = l >> 4;
  int n0 = blockIdx.x*32;
  int r0 = min(n0 + c, n-1);
  int r1 = min(n0 + 16 + c, n-1);
  f32x4 acc[2][4];
  #pragma unroll
  for (int m = 0; m < 2; m++)
    #pragma unroll
    for (int g = 0; g < 4; g++) acc[m][g] = (f32x4){0.f,0.f,0.f,0.f};

  #pragma unroll
  for (int kt = 0; kt < 4; ++kt){
    const unsigned short* A = (kt < 2) ? X : Hp;
    const unsigned short* Wp = (kt < 2) ? Wx : Wh;
    int ko = (kt & 1)*32 + kg*8;
    bf16x8 a0 = *reinterpret_cast<const bf16x8*>(A + (size_t)r0*64 + ko);
    bf16x8 a1 = *reinterpret_cast<const bf16x8*>(A + (size_t)r1*64 + ko);
    #pragma unroll
    for (int g = 0; g < 4; g++){
      bf16x8 b = *reinterpret_cast<const bf16x8*>(Wp + (size_t)(g*64 + w*16 + c)*64 + ko);
      acc[0][g] = mfma_bf16(a0, b, acc[0][g]);
      acc[1][g] = mfma_bf16(a1, b, acc[1][g]);
    }
  }
  int hid = w*16 + c;
  float bs0 = bi[hid]       + bh[hid];
  float bs1 = bi[hid + 64]  + bh[hid + 64];
  float bs2 = bi[hid + 128] + bh[hid + 128];
  float bs3 = bi[hid + 192] + bh[hid + 192];
  float wav = wa[hid];
  __shared__ float attp[4][32];
  #pragma unroll
  for (int m = 0; m < 2; m++){
    #pragma unroll
    for (int r = 0; r < 4; r++){
      int rl = m*16 + kg*4 + r;
      int grow = n0 + rl;
      int crow = min(grow, n-1);
      float gi = acc[m][0][r] + bs0;
      float gf = acc[m][1][r] + bs1;
      float gg = acc[m][2][r] + bs2;
      float go = acc[m][3][r] + bs3;
      float cp = bf2f(Cp[(size_t)crow*64 + hid]);
      float cc = fsigm(gf)*cp + fsigm(gi)*ftanh(gg);
      float hh = fsigm(go)*ftanh(cc);
      float s = hh*wav;
      s += __shfl_xor(s, 1, 16);
      s += __shfl_xor(s, 2, 16);
      s += __shfl_xor(s, 4, 16);
      s += __shfl_xor(s, 8, 16);
      if (c == 0) attp[w][rl] = s;
    }
  }
  __syncthreads();
  if (t < 32){
    int grow = n0 + t;
    if (grow < n) po[grow] = attp[0][t] + attp[1][t] + attp[2][t] + attp[3][t];
  }
}

// ================= JK attention + output GEMM + log_softmax =================
__global__ __launch_bounds__(256) void k_final(
    const unsigned short* __restrict__ x1b, const unsigned short* __restrict__ x2b,
    const float* __restrict__ pf0, const float* __restrict__ pf1,
    const float* __restrict__ pb0, const float* __restrict__ pb1,
    const float* __restrict__ Wout, float* __restrict__ out, int n)
{
  __shared__ __align__(16) float ws[NCLS][68];
  __shared__ __align__(16) float fs[32][68];
  int t = threadIdx.x;
  for (int i = t; i < NCLS*64; i += 256)
    ws[i>>6][i&63] = Wout[i];

  int n0 = blockIdx.x*32;
  int nd = t >> 3, q8 = t & 7;
  int g = n0 + nd;
  int eb = q8*8;
  if (g < n){
    float att0 = pf0[g] + pb1[g];
    float att1 = pf1[g] + pb0[g];
    float a0 = 1.f/(1.f + __expf(att1 - att0));
    float a1 = 1.f - a0;
    uint4 p1 = *reinterpret_cast<const uint4*>(x1b + (size_t)g*64 + eb);
    uint4 p2 = *reinterpret_cast<const uint4*>(x2b + (size_t)g*64 + eb);
    const unsigned* u1 = (const unsigned*)&p1;
    const unsigned* u2 = (const unsigned*)&p2;
    #pragma unroll
    for (int q = 0; q < 4; q++){
      float v1l = bf2f((unsigned short)u1[q]), v1h = bf2f((unsigned short)(u1[q]>>16));
      float v2l = bf2f((unsigned short)u2[q]), v2h = bf2f((unsigned short)(u2[q]>>16));
      fs[nd][eb + q*2 + 0] = a0*v1l + a1*v2l;
      fs[nd][eb + q*2 + 1] = a0*v1h + a1*v2h;
    }
  } else {
    #pragma unroll
    for (int q = 0; q < 8; q++) fs[nd][eb+q] = 0.f;
  }
  __syncthreads();

  float lg[5] = {0.f,0.f,0.f,0.f,0.f};
  #pragma unroll
  for (int k4 = 0; k4 < 16; k4++){
    float4 f = *reinterpret_cast<const float4*>(&fs[nd][k4*4]);
    #pragma unroll
    for (int q = 0; q < 5; q++){
      int cc = q8 + 8*q;
      float4 wv = *reinterpret_cast<const float4*>(&ws[cc][k4*4]);
      lg[q] = fmaf(f.x, wv.x, lg[q]);
      lg[q] = fmaf(f.y, wv.y, lg[q]);
      lg[q] = fmaf(f.z, wv.z, lg[q]);
      lg[q] = fmaf(f.w, wv.w, lg[q]);
    }
  }
  float mx = lg[0];
  #pragma unroll
  for (int q = 1; q < 5; q++) mx = fmaxf(mx, lg[q]);
  #pragma unroll
  for (int mk = 1; mk < 8; mk <<= 1) mx = fmaxf(mx, __shfl_xor(mx, mk, 64));
  float se = 0.f;
  #pragma unroll
  for (int q = 0; q < 5; q++) se += __expf(lg[q] - mx);
  #pragma unroll
  for (int mk = 1; mk < 8; mk <<= 1) se += __shfl_xor(se, mk, 64);
  float lse = __logf(se);
  if (g < n){
    #pragma unroll
    for (int q = 0; q < 5; q++)
      out[(size_t)g*NCLS + q8 + 8*q] = lg[q] - mx - lse;
  }
}

// ================= host =================
extern "C" void kernel_launch(void* const* d_in, const int* in_sizes, int n_in,
                              void* d_out, int out_size, void* d_ws, size_t ws_size,
                              hipStream_t stream)
{
  const float* x    = (const float*)d_in[0];
  const int*   ei   = (const int*)d_in[1];
  const float* W1   = (const float*)d_in[2];
  const float* a1s  = (const float*)d_in[3];
  const float* a1d  = (const float*)d_in[4];
  const float* b1   = (const float*)d_in[5];
  const float* W2   = (const float*)d_in[6];
  const float* a2s  = (const float*)d_in[7];
  const float* a2d  = (const float*)d_in[8];
  const float* b2   = (const float*)d_in[9];
  const float* Wih_f= (const float*)d_in[10];
  const float* Whh_f= (const float*)d_in[11];
  const float* bih_f= (const float*)d_in[12];
  const float* bhh_f= (const float*)d_in[13];
  const float* Wih_b= (const float*)d_in[14];
  const float* Whh_b= (const float*)d_in[15];
  const float* bih_b= (const float*)d_in[16];
  const float* bhh_b= (const float*)d_in[17];
  const float* watt = (const float*)d_in[18];
  const float* Wout = (const float*)d_in[20];
  float* out = (float*)d_out;

  int n = in_sizes[0] / F_IN;   // 100000
  int e = in_sizes[1] / 2;      // 1600000
  int nb = (n + BNODES - 1) >> BSH;       // buckets of 128 nodes (782)
  int B  = (e + n + CH - 1) / CH;         // partition blocks (~104)

  char* p = (char*)d_ws;
  auto alloc = [&](size_t b)->char*{ char* r = p; p += (b + 255) & ~(size_t)255; return r; };
  int* rowptr = (int*)alloc((size_t)(n+1)*4);
  int* colidx = (int*)alloc((size_t)(e+n)*4);
  unsigned* bedges = (unsigned*)alloc((size_t)(e+n)*4);
  int* bhist  = (int*)alloc((size_t)B*nb*4);
  int* bcnt   = (int*)alloc((size_t)(nb+1)*4);
  int* bbase  = (int*)alloc((size_t)(nb+1)*4);
  unsigned short* hbuf = (unsigned short*)alloc((size_t)n*64*2);   // bf16 H
  unsigned short* alsb = (unsigned short*)alloc((size_t)n*8*2);    // bf16 als
  float* ald  = (float*)alloc((size_t)n*8*4);
  unsigned short* x1b = (unsigned short*)alloc((size_t)n*64*2);
  unsigned short* x2b = (unsigned short*)alloc((size_t)n*64*2);
  unsigned short* hf0 = (unsigned short*)alloc((size_t)n*64*2);
  unsigned short* cf0 = (unsigned short*)alloc((size_t)n*64*2);
  unsigned short* hb0 = (unsigned short*)alloc((size_t)n*64*2);
  unsigned short* cb0 = (unsigned short*)alloc((size_t)n*64*2);
  float* pf0 = (float*)alloc((size_t)n*4);
  float* pf1 = (float*)alloc((size_t)n*4);
  float* pb0 = (float*)alloc((size_t)n*4);
  float* pb1 = (float*)alloc((size_t)n*4);
  unsigned short* W1T = (unsigned short*)alloc((size_t)64*512*2);
  unsigned short* W2T = (unsigned short*)alloc((size_t)64*64*2);
  unsigned short* Wfx = (unsigned short*)alloc((size_t)256*64*2);
  unsigned short* Wfh = (unsigned short*)alloc((size_t)256*64*2);
  unsigned short* Wbx = (unsigned short*)alloc((size_t)256*64*2);
  unsigned short* Wbh = (unsigned short*)alloc((size_t)256*64*2);

  // ---- CSR build (block-aggregated partition, no global atomics) ----
  k_pcount<<<B, 256, 0, stream>>>(ei, e, n, nb, bhist);
  k_pscan1<<<(nb+255)/256, 256, 0, stream>>>(bhist, nb, B, bcnt);
  k_pscan2<<<1, 256, 0, stream>>>(bcnt, nb, e+n, bbase, rowptr, n);
  k_pscatter<<<B, 256, 0, stream>>>(ei, e, n, nb, bhist, bbase, bedges);
  k_bbuild<<<nb, 256, 0, stream>>>(bedges, bbase, rowptr, colidx, n);

  // ---- weight conversion (single dispatch) ----
  k_prep<<<400, 256, 0, stream>>>(W1, W2, Wih_f, Whh_f, Wih_b, Whh_b,
                                  W1T, W2T, Wfx, Wfh, Wbx, Wbh);

  // ---- GAT layers (attention logits fused into GEMM epilogue) ----
  int gblk = (n + 63)/64;
  k_mf_gemm<512,true ><<<gblk, 256, 0, stream>>>(x, nullptr, W1T, a1s, a1d, hbuf, alsb, ald, n);
  k_agg<true ><<<(n+7)/8, 256, 0, stream>>>(rowptr, colidx, hbuf, alsb, ald, b1, x1b, n);
  k_mf_gemm<64,false ><<<gblk, 256, 0, stream>>>(nullptr, x1b, W2T, a2s, a2d, hbuf, alsb, ald, n);
  k_agg<false><<<(n+7)/8, 256, 0, stream>>>(rowptr, colidx, hbuf, alsb, ald, b2, x2b, n);

  // ---- JK LSTM (both directions fused via grid.y) ----
  dim3 lgrid((n + 31)/32, 2);
  k_lstm0<<<lgrid, 256, 0, stream>>>(x1b, x2b, Wfx, Wbx, bih_f, bhh_f, bih_b, bhh_b,
                                     watt, hf0, cf0, hb0, cb0, pf0, pb0, n);
  k_lstm1<<<lgrid, 256, 0, stream>>>(x1b, x2b, hf0, cf0, hb0, cb0,
                                     Wfx, Wfh, Wbx, Wbh, bih_f, bhh_f, bih_b, bhh_b,
                                     watt, pf1, pb1, n);

  // ---- output layer ----
  k_final<<<(n+3)/4, 256, 0, stream>>>(x1b, x2b, pf0, pf1, pb0, pb1, Wout, out, n);
}

// Round 8
// 497.930 us; speedup vs baseline: 2.0132x; 1.1297x over previous
//
#include <hip/hip_runtime.h>
#include <math.h>

#define F_IN 512
#define NCLS 40
#define BSH 7                 // 128 nodes per bucket
#define BNODES (1 << BSH)
#define CH 16384              // edges per partition block

typedef __attribute__((ext_vector_type(8))) short bf16x8;
typedef __attribute__((ext_vector_type(4))) float f32x4;

__device__ __forceinline__ f32x4 mfma_bf16(bf16x8 a, bf16x8 b, f32x4 c){
  return __builtin_amdgcn_mfma_f32_16x16x32_bf16(a, b, c, 0, 0, 0);
}
__device__ __forceinline__ float fsigm(float x){ return 1.f/(1.f+__expf(-x)); }
__device__ __forceinline__ float ftanh(float x){ return 1.f - 2.f/(__expf(2.f*x)+1.f); }
__device__ __forceinline__ unsigned short f2bf(float f){
  unsigned u = __float_as_uint(f);
  return (unsigned short)((u + 0x7fffu + ((u>>16)&1u)) >> 16);
}
__device__ __forceinline__ float bf2f(unsigned short h){
  return __uint_as_float(((unsigned)h) << 16);
}

// ================= CSR build: block-aggregated partition (no global atomics) ========
__global__ __launch_bounds__(256) void k_pcount(const int* __restrict__ ei, int e, int n,
                                                int nb, int* __restrict__ bhist){
  __shared__ int h[1024];
  int b = blockIdx.x, t = threadIdx.x;
  for (int i = t; i < nb; i += 256) h[i] = 0;
  __syncthreads();
  int tot = e + n;
  int base = b*CH;
  int lim = min(base + CH, tot);
  for (int i = base + t; i < lim; i += 256){
    int d = (i < e) ? ei[e + i] : (i - e);
    atomicAdd(&h[d >> BSH], 1);
  }
  __syncthreads();
  for (int i = t; i < nb; i += 256) bhist[(size_t)b*nb + i] = h[i];
}

__global__ __launch_bounds__(256) void k_pscan1(int* __restrict__ bhist, int nb, int B,
                                                int* __restrict__ bcnt){
  int i = blockIdx.x*256 + threadIdx.x;
  if (i >= nb) return;
  int run = 0;
  for (int b = 0; b < B; b++){
    int v = bhist[(size_t)b*nb + i];
    bhist[(size_t)b*nb + i] = run;
    run += v;
  }
  bcnt[i] = run;
}

__global__ __launch_bounds__(256) void k_pscan2(const int* __restrict__ bcnt, int nb, int tot,
                                                int* __restrict__ bbase,
                                                int* __restrict__ rowptr, int n){
  __shared__ int sb[256];
  __shared__ int carry;
  int t = threadIdx.x;
  if (t == 0) carry = 0;
  __syncthreads();
  for (int c0 = 0; c0 < nb; c0 += 256){
    int v = (c0 + t < nb) ? bcnt[c0 + t] : 0;
    sb[t] = v; __syncthreads();
    for (int off = 1; off < 256; off <<= 1){
      int u = (t >= off) ? sb[t-off] : 0; __syncthreads();
      sb[t] += u; __syncthreads();
    }
    if (c0 + t < nb) bbase[c0 + t] = carry + sb[t] - v;
    __syncthreads();
    if (t == 0) carry += sb[255];
    __syncthreads();
  }
  if (t == 0){ bbase[nb] = carry; rowptr[n] = tot; }
}

__global__ __launch_bounds__(256) void k_pscatter(const int* __restrict__ ei, int e, int n,
                                                  int nb, const int* __restrict__ bhist,
                                                  const int* __restrict__ bbase,
                                                  unsigned* __restrict__ bedges){
  __shared__ int cur[1024];
  int b = blockIdx.x, t = threadIdx.x;
  for (int i = t; i < nb; i += 256)
    cur[i] = bbase[i] + bhist[(size_t)b*nb + i];
  __syncthreads();
  int tot = e + n;
  int base = b*CH;
  int lim = min(base + CH, tot);
  for (int i = base + t; i < lim; i += 256){
    int s, d;
    if (i < e){ s = ei[i]; d = ei[e + i]; } else { s = i - e; d = s; }
    int pos = atomicAdd(&cur[d >> BSH], 1);
    bedges[pos] = (unsigned)s | ((unsigned)(d & (BNODES-1)) << 20);
  }
}

__global__ __launch_bounds__(256) void k_bbuild(const unsigned* __restrict__ bedges,
                                                const int* __restrict__ bbase,
                                                int* __restrict__ rowptr, int* __restrict__ col, int n){
  int b = blockIdx.x;
  int t = threadIdx.x;
  __shared__ int hist[BNODES];
  __shared__ int sc[BNODES];
  __shared__ int cur[BNODES];
  int beg = bbase[b], end = bbase[b+1];
  if (t < BNODES) hist[t] = 0;
  __syncthreads();
  for (int i = beg + t; i < end; i += 256)
    atomicAdd(&hist[bedges[i] >> 20], 1);
  __syncthreads();
  int v = (t < BNODES) ? hist[t] : 0;
  if (t < BNODES) sc[t] = v;
  __syncthreads();
  for (int off = 1; off < BNODES; off <<= 1){
    int u = (t >= off && t < BNODES) ? sc[t-off] : 0;
    __syncthreads();
    if (t < BNODES) sc[t] += u;
    __syncthreads();
  }
  if (t < BNODES){
    int excl = sc[t] - v;
    int node = (b << BSH) + t;
    if (node < n) rowptr[node] = beg + excl;
    cur[t] = excl;
  }
  __syncthreads();
  for (int i = beg + t; i < end; i += 256){
    unsigned pk = bedges[i];
    int pos = atomicAdd(&cur[pk >> 20], 1);
    col[beg + pos] = (int)(pk & 0xFFFFFu);
  }
}

// ================= fused weight prep (all conversions, 1 dispatch) =================
__global__ __launch_bounds__(256) void k_prep(
    const float* __restrict__ W1, const float* __restrict__ W2,
    const float* __restrict__ Wihf, const float* __restrict__ Whhf,
    const float* __restrict__ Wihb, const float* __restrict__ Whhb,
    unsigned short* __restrict__ W1T, unsigned short* __restrict__ W2T,
    unsigned short* __restrict__ Wfx, unsigned short* __restrict__ Wfh,
    unsigned short* __restrict__ Wbx, unsigned short* __restrict__ Wbh)
{
  int i = blockIdx.x*256 + threadIdx.x;
  if (i < 32768){                 // W1 [512][64] -> W1T [64][512]
    int k = i >> 6, c = i & 63;
    W1T[c*512 + k] = f2bf(W1[i]);
  } else if (i < 36864){          // W2 [64][64] -> W2T [64][64]
    int j = i - 32768; int k = j >> 6, c = j & 63;
    W2T[c*64 + k] = f2bf(W2[j]);
  } else if (i < 102400){         // 4 x [256][64] straight bf16 copies
    int j = i - 36864;
    int which = j >> 14, o = j & 16383;
    const float* src = which==0 ? Wihf : which==1 ? Whhf : which==2 ? Wihb : Whhb;
    unsigned short* dst = which==0 ? Wfx : which==1 ? Wfh : which==2 ? Wbx : Wbh;
    dst[o] = f2bf(src[o]);
  }
}

// ================= MFMA GEMM + fused attention-logit epilogue =================
template<int K, bool SRCF32>
__global__ __launch_bounds__(256) void k_mf_gemm(
    const float* __restrict__ Xf, const unsigned short* __restrict__ Xh,
    const unsigned short* __restrict__ WT,
    const float* __restrict__ as_, const float* __restrict__ ad_,
    unsigned short* __restrict__ Hb, unsigned short* __restrict__ alsb,
    float* __restrict__ ald, int n)
{
  int t = threadIdx.x;
  int w = t >> 6, l = t & 63;
  int c = l & 15, kg = l >> 4;
  int n0 = blockIdx.x*64 + w*16;
  int row = min(n0 + c, n-1);
  f32x4 acc[4];
  #pragma unroll
  for (int j = 0; j < 4; j++) acc[j] = (f32x4){0.f,0.f,0.f,0.f};

  #pragma unroll 4
  for (int kt = 0; kt < K/32; ++kt){
    int ko = kt*32 + kg*8;
    bf16x8 a;
    if (SRCF32){
      const float* xp = Xf + (size_t)row*K + ko;
      float4 u0 = *reinterpret_cast<const float4*>(xp);
      float4 u1 = *reinterpret_cast<const float4*>(xp + 4);
      a[0]=(short)f2bf(u0.x); a[1]=(short)f2bf(u0.y); a[2]=(short)f2bf(u0.z); a[3]=(short)f2bf(u0.w);
      a[4]=(short)f2bf(u1.x); a[5]=(short)f2bf(u1.y); a[6]=(short)f2bf(u1.z); a[7]=(short)f2bf(u1.w);
    } else {
      a = *reinterpret_cast<const bf16x8*>(Xh + (size_t)row*K + ko);
    }
    #pragma unroll
    for (int j = 0; j < 4; j++){
      bf16x8 b = *reinterpret_cast<const bf16x8*>(WT + (size_t)(j*16 + c)*K + ko);
      acc[j] = mfma_bf16(a, b, acc[j]);
    }
  }
  float asl[4], adl[4];
  #pragma unroll
  for (int j = 0; j < 4; j++){ asl[j] = as_[j*16 + c]; adl[j] = ad_[j*16 + c]; }
  #pragma unroll
  for (int j = 0; j < 4; j++){
    #pragma unroll
    for (int r = 0; r < 4; r++){
      int grow = n0 + kg*4 + r;
      float v = acc[j][r];
      if (grow < n) Hb[(size_t)grow*64 + j*16 + c] = f2bf(v);
      float sv = v*asl[j];
      float dv = v*adl[j];
      sv += __shfl_xor(sv, 1, 64); sv += __shfl_xor(sv, 2, 64); sv += __shfl_xor(sv, 4, 64);
      dv += __shfl_xor(dv, 1, 64); dv += __shfl_xor(dv, 2, 64); dv += __shfl_xor(dv, 4, 64);
      if ((c & 7) == 0 && grow < n){
        int head = j*2 + (c >> 3);
        alsb[(size_t)grow*8 + head] = f2bf(sv);
        ald [(size_t)grow*8 + head] = dv;
      }
    }
  }
}

// ================= GAT aggregation: 4 nodes/wave (16 lanes/node), 8B H loads ========
template<bool DO_ELU>
__global__ __launch_bounds__(256) void k_agg(
    const int* __restrict__ rowptr, const int* __restrict__ col,
    const unsigned short* __restrict__ Hb, const unsigned short* __restrict__ alsb,
    const float* __restrict__ ald, const float* __restrict__ bias,
    unsigned short* __restrict__ outb, int n)
{
  int grp = threadIdx.x >> 4;           // 16 groups per block
  int ln  = threadIdx.x & 15;           // 4 channels per lane
  int node = blockIdx.x*16 + grp;
  if (node >= n) return;
  int hh = ln >> 1;                     // head (2 lanes per head)
  float adv = ald[node*8 + hh];
  int beg = rowptr[node], end = rowptr[node+1];
  const unsigned short* Hp = Hb + ln*4;
  const unsigned short* ap = alsb + hh;

  float ssum = 0.f, acc0 = 0.f, acc1 = 0.f, acc2 = 0.f, acc3 = 0.f;
  int p = beg;
  int s0 = col[p];
  int s1 = (p+1 < end) ? col[p+1] : s0;
  int s2 = (p+2 < end) ? col[p+2] : s0;
  int s3 = (p+3 < end) ? col[p+3] : s0;
  float a0 = bf2f(ap[s0*8]), a1 = bf2f(ap[s1*8]);
  float a2 = bf2f(ap[s2*8]), a3 = bf2f(ap[s3*8]);
  ushort4 h0 = *reinterpret_cast<const ushort4*>(Hp + (size_t)s0*64);
  ushort4 h1 = *reinterpret_cast<const ushort4*>(Hp + (size_t)s1*64);
  ushort4 h2 = *reinterpret_cast<const ushort4*>(Hp + (size_t)s2*64);
  ushort4 h3 = *reinterpret_cast<const ushort4*>(Hp + (size_t)s3*64);

  while (p < end){
    int np = p + 4;
    float b0=a0, b1=a1, b2=a2, b3=a3;
    ushort4 g0=h0, g1=h1, g2=h2, g3=h3;
    if (np < end){
      s0 = col[np];
      s1 = (np+1 < end) ? col[np+1] : s0;
      s2 = (np+2 < end) ? col[np+2] : s0;
      s3 = (np+3 < end) ? col[np+3] : s0;
      a0 = bf2f(ap[s0*8]); a1 = bf2f(ap[s1*8]);
      a2 = bf2f(ap[s2*8]); a3 = bf2f(ap[s3*8]);
      h0 = *reinterpret_cast<const ushort4*>(Hp + (size_t)s0*64);
      h1 = *reinterpret_cast<const ushort4*>(Hp + (size_t)s1*64);
      h2 = *reinterpret_cast<const ushort4*>(Hp + (size_t)s2*64);
      h3 = *reinterpret_cast<const ushort4*>(Hp + (size_t)s3*64);
    }
    float e0 = b0 + adv; e0 = (e0>0.f)?e0:0.2f*e0;
    float e1 = b1 + adv; e1 = (e1>0.f)?e1:0.2f*e1;
    float e2 = b2 + adv; e2 = (e2>0.f)?e2:0.2f*e2;
    float e3 = b3 + adv; e3 = (e3>0.f)?e3:0.2f*e3;
    float x0 = __expf(e0);
    float x1 = (p+1 < end) ? __expf(e1) : 0.f;
    float x2 = (p+2 < end) ? __expf(e2) : 0.f;
    float x3 = (p+3 < end) ? __expf(e3) : 0.f;
    ssum += (x0 + x1) + (x2 + x3);
    acc0 = fmaf(x0, bf2f(g0.x), acc0); acc1 = fmaf(x0, bf2f(g0.y), acc1);
    acc2 = fmaf(x0, bf2f(g0.z), acc2); acc3 = fmaf(x0, bf2f(g0.w), acc3);
    acc0 = fmaf(x1, bf2f(g1.x), acc0); acc1 = fmaf(x1, bf2f(g1.y), acc1);
    acc2 = fmaf(x1, bf2f(g1.z), acc2); acc3 = fmaf(x1, bf2f(g1.w), acc3);
    acc0 = fmaf(x2, bf2f(g2.x), acc0); acc1 = fmaf(x2, bf2f(g2.y), acc1);
    acc2 = fmaf(x2, bf2f(g2.z), acc2); acc3 = fmaf(x2, bf2f(g2.w), acc3);
    acc0 = fmaf(x3, bf2f(g3.x), acc0); acc1 = fmaf(x3, bf2f(g3.y), acc1);
    acc2 = fmaf(x3, bf2f(g3.z), acc2); acc3 = fmaf(x3, bf2f(g3.w), acc3);
    p = np;
  }
  float inv = 1.f/ssum;
  float o0 = acc0*inv + bias[ln*4+0];
  float o1 = acc1*inv + bias[ln*4+1];
  float o2 = acc2*inv + bias[ln*4+2];
  float o3 = acc3*inv + bias[ln*4+3];
  if (DO_ELU){
    o0 = (o0 > 0.f) ? o0 : (__expf(o0) - 1.f);
    o1 = (o1 > 0.f) ? o1 : (__expf(o1) - 1.f);
    o2 = (o2 > 0.f) ? o2 : (__expf(o2) - 1.f);
    o3 = (o3 > 0.f) ? o3 : (__expf(o3) - 1.f);
  }
  ushort4 pk;
  pk.x = f2bf(o0); pk.y = f2bf(o1); pk.z = f2bf(o2); pk.w = f2bf(o3);
  *reinterpret_cast<ushort4*>(outb + (size_t)node*64 + ln*4) = pk;
}

// ================= fused bidirectional 2-step LSTM (one dispatch) =================
// grid (nblk, 2): y = direction. Step0 gates from X0; h0 exchanged via LDS
// (c0 stays in registers — step1 epilogue uses the same (row,col) ownership).
__global__ __launch_bounds__(256) void k_lstm(
    const unsigned short* __restrict__ X1b, const unsigned short* __restrict__ X2b,
    const unsigned short* __restrict__ Wfx, const unsigned short* __restrict__ Wfh,
    const unsigned short* __restrict__ Wbx, const unsigned short* __restrict__ Wbh,
    const float* __restrict__ bihf, const float* __restrict__ bhhf,
    const float* __restrict__ bihb, const float* __restrict__ bhhb,
    const float* __restrict__ watt,
    float* __restrict__ pf0, float* __restrict__ pf1,
    float* __restrict__ pb0, float* __restrict__ pb1, int n)
{
  int dir = blockIdx.y;
  const unsigned short* X0 = dir ? X2b : X1b;   // step0 input
  const unsigned short* X1 = dir ? X1b : X2b;   // step1 input
  const unsigned short* Wx = dir ? Wbx : Wfx;
  const unsigned short* Wh = dir ? Wbh : Wfh;
  const float* bi = dir ? bihb : bihf;
  const float* bh = dir ? bhhb : bhhf;
  const float* wa = watt + dir*64;
  float* po0 = dir ? pb0 : pf0;
  float* po1 = dir ? pb1 : pf1;

  __shared__ unsigned short hls[32][72];   // padded: b128 reads -> 2-way (free)
  __shared__ float attp[2][4][32];

  int t = threadIdx.x;
  int w = t >> 6, l = t & 63;
  int c = l & 15, kg = l >> 4;
  int n0 = blockIdx.x*32;
  int r0 = min(n0 + c, n-1);
  int r1 = min(n0 + 16 + c, n-1);

  int hid = w*16 + c;
  float bs0 = bi[hid]       + bh[hid];
  float bs1 = bi[hid + 64]  + bh[hid + 64];
  float bs2 = bi[hid + 128] + bh[hid + 128];
  float bs3 = bi[hid + 192] + bh[hid + 192];
  float wav = wa[hid];

  // ---- step 0: gates = X0 @ Wx^T ----
  f32x4 acc[2][4];
  #pragma unroll
  for (int m = 0; m < 2; m++)
    #pragma unroll
    for (int g = 0; g < 4; g++) acc[m][g] = (f32x4){0.f,0.f,0.f,0.f};

  #pragma unroll
  for (int kt = 0; kt < 2; ++kt){
    int ko = kt*32 + kg*8;
    bf16x8 a0 = *reinterpret_cast<const bf16x8*>(X0 + (size_t)r0*64 + ko);
    bf16x8 a1 = *reinterpret_cast<const bf16x8*>(X0 + (size_t)r1*64 + ko);
    #pragma unroll
    for (int g = 0; g < 4; g++){
      bf16x8 b = *reinterpret_cast<const bf16x8*>(Wx + (size_t)(g*64 + hid)*64 + ko);
      acc[0][g] = mfma_bf16(a0, b, acc[0][g]);
      acc[1][g] = mfma_bf16(a1, b, acc[1][g]);
    }
  }
  float creg[2][4];
  #pragma unroll
  for (int m = 0; m < 2; m++){
    #pragma unroll
    for (int r = 0; r < 4; r++){
      int rl = m*16 + kg*4 + r;
      float gi = acc[m][0][r] + bs0;
      float gg = acc[m][2][r] + bs2;
      float go = acc[m][3][r] + bs3;
      float cc = fsigm(gi)*ftanh(gg);
      float hh = fsigm(go)*ftanh(cc);
      creg[m][r] = cc;
      hls[rl][hid] = f2bf(hh);
      float s = hh*wav;
      s += __shfl_xor(s, 1, 16);
      s += __shfl_xor(s, 2, 16);
      s += __shfl_xor(s, 4, 16);
      s += __shfl_xor(s, 8, 16);
      if (c == 0) attp[0][w][rl] = s;
    }
  }
  __syncthreads();

  // ---- step 1: gates = X1 @ Wx^T + h0 @ Wh^T ----
  #pragma unroll
  for (int m = 0; m < 2; m++)
    #pragma unroll
    for (int g = 0; g < 4; g++) acc[m][g] = (f32x4){0.f,0.f,0.f,0.f};

  #pragma unroll
  for (int kt = 0; kt < 4; ++kt){
    int ko = (kt & 1)*32 + kg*8;
    bf16x8 a0, a1;
    if (kt < 2){
      a0 = *reinterpret_cast<const bf16x8*>(X1 + (size_t)r0*64 + ko);
      a1 = *reinterpret_cast<const bf16x8*>(X1 + (size_t)r1*64 + ko);
    } else {
      a0 = *reinterpret_cast<const bf16x8*>(&hls[c][ko]);
      a1 = *reinterpret_cast<const bf16x8*>(&hls[16 + c][ko]);
    }
    const unsigned short* Wp = (kt < 2) ? Wx : Wh;
    #pragma unroll
    for (int g = 0; g < 4; g++){
      bf16x8 b = *reinterpret_cast<const bf16x8*>(Wp + (size_t)(g*64 + hid)*64 + ko);
      acc[0][g] = mfma_bf16(a0, b, acc[0][g]);
      acc[1][g] = mfma_bf16(a1, b, acc[1][g]);
    }
  }
  #pragma unroll
  for (int m = 0; m < 2; m++){
    #pragma unroll
    for (int r = 0; r < 4; r++){
      int rl = m*16 + kg*4 + r;
      float gi = acc[m][0][r] + bs0;
      float gf = acc[m][1][r] + bs1;
      float gg = acc[m][2][r] + bs2;
      float go = acc[m][3][r] + bs3;
      float cc = fsigm(gf)*creg[m][r] + fsigm(gi)*ftanh(gg);
      float hh = fsigm(go)*ftanh(cc);
      float s = hh*wav;
      s += __shfl_xor(s, 1, 16);
      s += __shfl_xor(s, 2, 16);
      s += __shfl_xor(s, 4, 16);
      s += __shfl_xor(s, 8, 16);
      if (c == 0) attp[1][w][rl] = s;
    }
  }
  __syncthreads();
  if (t < 32){
    int grow = n0 + t;
    if (grow < n) po0[grow] = attp[0][0][t] + attp[0][1][t] + attp[0][2][t] + attp[0][3][t];
  } else if (t < 64){
    int rr = t - 32;
    int grow = n0 + rr;
    if (grow < n) po1[grow] = attp[1][0][rr] + attp[1][1][rr] + attp[1][2][rr] + attp[1][3][rr];
  }
}

// ================= JK attention + output GEMM + log_softmax =================
__global__ __launch_bounds__(256) void k_final(
    const unsigned short* __restrict__ x1b, const unsigned short* __restrict__ x2b,
    const float* __restrict__ pf0, const float* __restrict__ pf1,
    const float* __restrict__ pb0, const float* __restrict__ pb1,
    const float* __restrict__ Wout, float* __restrict__ out, int n)
{
  __shared__ __align__(16) float ws[NCLS][68];
  __shared__ __align__(16) float fs[32][68];
  int t = threadIdx.x;
  for (int i = t; i < NCLS*64; i += 256)
    ws[i>>6][i&63] = Wout[i];

  int n0 = blockIdx.x*32;
  int nd = t >> 3, q8 = t & 7;
  int g = n0 + nd;
  int eb = q8*8;
  if (g < n){
    float att0 = pf0[g] + pb1[g];
    float att1 = pf1[g] + pb0[g];
    float a0 = 1.f/(1.f + __expf(att1 - att0));
    float a1 = 1.f - a0;
    uint4 p1 = *reinterpret_cast<const uint4*>(x1b + (size_t)g*64 + eb);
    uint4 p2 = *reinterpret_cast<const uint4*>(x2b + (size_t)g*64 + eb);
    const unsigned* u1 = (const unsigned*)&p1;
    const unsigned* u2 = (const unsigned*)&p2;
    #pragma unroll
    for (int q = 0; q < 4; q++){
      float v1l = bf2f((unsigned short)u1[q]), v1h = bf2f((unsigned short)(u1[q]>>16));
      float v2l = bf2f((unsigned short)u2[q]), v2h = bf2f((unsigned short)(u2[q]>>16));
      fs[nd][eb + q*2 + 0] = a0*v1l + a1*v2l;
      fs[nd][eb + q*2 + 1] = a0*v1h + a1*v2h;
    }
  } else {
    #pragma unroll
    for (int q = 0; q < 8; q++) fs[nd][eb+q] = 0.f;
  }
  __syncthreads();

  float lg[5] = {0.f,0.f,0.f,0.f,0.f};
  #pragma unroll
  for (int k4 = 0; k4 < 16; k4++){
    float4 f = *reinterpret_cast<const float4*>(&fs[nd][k4*4]);
    #pragma unroll
    for (int q = 0; q < 5; q++){
      int cc = q8 + 8*q;
      float4 wv = *reinterpret_cast<const float4*>(&ws[cc][k4*4]);
      lg[q] = fmaf(f.x, wv.x, lg[q]);
      lg[q] = fmaf(f.y, wv.y, lg[q]);
      lg[q] = fmaf(f.z, wv.z, lg[q]);
      lg[q] = fmaf(f.w, wv.w, lg[q]);
    }
  }
  float mx = lg[0];
  #pragma unroll
  for (int q = 1; q < 5; q++) mx = fmaxf(mx, lg[q]);
  #pragma unroll
  for (int mk = 1; mk < 8; mk <<= 1) mx = fmaxf(mx, __shfl_xor(mx, mk, 64));
  float se = 0.f;
  #pragma unroll
  for (int q = 0; q < 5; q++) se += __expf(lg[q] - mx);
  #pragma unroll
  for (int mk = 1; mk < 8; mk <<= 1) se += __shfl_xor(se, mk, 64);
  float lse = __logf(se);
  if (g < n){
    #pragma unroll
    for (int q = 0; q < 5; q++)
      out[(size_t)g*NCLS + q8 + 8*q] = lg[q] - mx - lse;
  }
}

// ================= host =================
extern "C" void kernel_launch(void* const* d_in, const int* in_sizes, int n_in,
                              void* d_out, int out_size, void* d_ws, size_t ws_size,
                              hipStream_t stream)
{
  const float* x    = (const float*)d_in[0];
  const int*   ei   = (const int*)d_in[1];
  const float* W1   = (const float*)d_in[2];
  const float* a1s  = (const float*)d_in[3];
  const float* a1d  = (const float*)d_in[4];
  const float* b1   = (const float*)d_in[5];
  const float* W2   = (const float*)d_in[6];
  const float* a2s  = (const float*)d_in[7];
  const float* a2d  = (const float*)d_in[8];
  const float* b2   = (const float*)d_in[9];
  const float* Wih_f= (const float*)d_in[10];
  const float* Whh_f= (const float*)d_in[11];
  const float* bih_f= (const float*)d_in[12];
  const float* bhh_f= (const float*)d_in[13];
  const float* Wih_b= (const float*)d_in[14];
  const float* Whh_b= (const float*)d_in[15];
  const float* bih_b= (const float*)d_in[16];
  const float* bhh_b= (const float*)d_in[17];
  const float* watt = (const float*)d_in[18];
  const float* Wout = (const float*)d_in[20];
  float* out = (float*)d_out;

  int n = in_sizes[0] / F_IN;   // 100000
  int e = in_sizes[1] / 2;      // 1600000
  int nb = (n + BNODES - 1) >> BSH;       // buckets of 128 nodes (782)
  int B  = (e + n + CH - 1) / CH;         // partition blocks (~104)

  char* p = (char*)d_ws;
  auto alloc = [&](size_t b)->char*{ char* r = p; p += (b + 255) & ~(size_t)255; return r; };
  int* rowptr = (int*)alloc((size_t)(n+1)*4);
  int* colidx = (int*)alloc((size_t)(e+n)*4);
  unsigned* bedges = (unsigned*)alloc((size_t)(e+n)*4);
  int* bhist  = (int*)alloc((size_t)B*nb*4);
  int* bcnt   = (int*)alloc((size_t)(nb+1)*4);
  int* bbase  = (int*)alloc((size_t)(nb+1)*4);
  unsigned short* hbuf = (unsigned short*)alloc((size_t)n*64*2);   // bf16 H
  unsigned short* alsb = (unsigned short*)alloc((size_t)n*8*2);    // bf16 als
  float* ald  = (float*)alloc((size_t)n*8*4);
  unsigned short* x1b = (unsigned short*)alloc((size_t)n*64*2);
  unsigned short* x2b = (unsigned short*)alloc((size_t)n*64*2);
  float* pf0 = (float*)alloc((size_t)n*4);
  float* pf1 = (float*)alloc((size_t)n*4);
  float* pb0 = (float*)alloc((size_t)n*4);
  float* pb1 = (float*)alloc((size_t)n*4);
  unsigned short* W1T = (unsigned short*)alloc((size_t)64*512*2);
  unsigned short* W2T = (unsigned short*)alloc((size_t)64*64*2);
  unsigned short* Wfx = (unsigned short*)alloc((size_t)256*64*2);
  unsigned short* Wfh = (unsigned short*)alloc((size_t)256*64*2);
  unsigned short* Wbx = (unsigned short*)alloc((size_t)256*64*2);
  unsigned short* Wbh = (unsigned short*)alloc((size_t)256*64*2);

  // ---- CSR build (block-aggregated partition, no global atomics) ----
  k_pcount<<<B, 256, 0, stream>>>(ei, e, n, nb, bhist);
  k_pscan1<<<(nb+255)/256, 256, 0, stream>>>(bhist, nb, B, bcnt);
  k_pscan2<<<1, 256, 0, stream>>>(bcnt, nb, e+n, bbase, rowptr, n);
  k_pscatter<<<B, 256, 0, stream>>>(ei, e, n, nb, bhist, bbase, bedges);
  k_bbuild<<<nb, 256, 0, stream>>>(bedges, bbase, rowptr, colidx, n);

  // ---- weight conversion (single dispatch) ----
  k_prep<<<400, 256, 0, stream>>>(W1, W2, Wih_f, Whh_f, Wih_b, Whh_b,
                                  W1T, W2T, Wfx, Wfh, Wbx, Wbh);

  // ---- GAT layers (attention logits fused into GEMM epilogue) ----
  int gblk = (n + 63)/64;
  k_mf_gemm<512,true ><<<gblk, 256, 0, stream>>>(x, nullptr, W1T, a1s, a1d, hbuf, alsb, ald, n);
  k_agg<true ><<<(n+15)/16, 256, 0, stream>>>(rowptr, colidx, hbuf, alsb, ald, b1, x1b, n);
  k_mf_gemm<64,false ><<<gblk, 256, 0, stream>>>(nullptr, x1b, W2T, a2s, a2d, hbuf, alsb, ald, n);
  k_agg<false><<<(n+15)/16, 256, 0, stream>>>(rowptr, colidx, hbuf, alsb, ald, b2, x2b, n);

  // ---- JK LSTM: both directions, both steps, one dispatch ----
  dim3 lgrid((n + 31)/32, 2);
  k_lstm<<<lgrid, 256, 0, stream>>>(x1b, x2b, Wfx, Wfh, Wbx, Wbh,
                                    bih_f, bhh_f, bih_b, bhh_b,
                                    watt, pf0, pf1, pb0, pb1, n);

  // ---- output layer ----
  k_final<<<(n+3)/4, 256, 0, stream>>>(x1b, x2b, pf0, pf1, pb0, pb1, Wout, out, n);
}